// Round 8
// baseline (2845.625 us; speedup 1.0000x reference)
//
#include <hip/hip_runtime.h>
#include <hip/hip_bf16.h>

#define DEV __device__ __forceinline__

constexpr int Mn  = 30000;   // nodes (B=1)
constexpr int Tt  = 12;
constexpr int CIN = 16;
constexpr int Hh  = 64;
constexpr int Gg  = 192;     // 3H
constexpr int C2  = 128;     // 2H
constexpr int Ee  = 960000;  // edges per timestep (bidirectional)
constexpr int HC  = 128;
constexpr int Oo  = 12;
constexpr int KW  = 128;
constexpr int SEGS= 938;     // 32-row segments per t (938*32 >= 30000)
constexpr int NB  = 235;     // 128-row buckets per t (235*128 >= 30000)
constexpr int EPB = 8192;    // edges per block for bcnt/part2
constexpr int BPT = 118;     // ceil(Ee/EPB)
constexpr int CHK = 21;      // chunks per t for power iteration (252 blocks total)
constexpr int RC  = 1440;    // rows per chunk (16B-aligned chunk base; 21*1440 >= 30000)
constexpr int NRND= 76;      // 75 power rounds + 1 Rayleigh round
constexpr int NF4A= 21*256;  // phase-A float4 count (rows [r0, r0+1024) per chunk)
constexpr int NF4B= 20*104 + 44; // phase-B float4 count (rows [r0+1024, r1) per chunk)

DEV float bf2f(__hip_bfloat16 v){ return __bfloat162float(v); }
DEV __hip_bfloat16 f2bf(float v){ return __float2bfloat16(v); }
DEV float sigm(float x){ return __builtin_amdgcn_rcpf(1.f + __expf(-x)); }
DEV float tanh_f(float x){ return 1.f - 2.f*__builtin_amdgcn_rcpf(__expf(2.f*x) + 1.f); }

// agent-scope (device-coherent, sc1) accessors for cross-XCD flags/u-stores
DEV float aload_f(const float* p){ return __hip_atomic_load(p, __ATOMIC_RELAXED, __HIP_MEMORY_SCOPE_AGENT); }
DEV void  astore_f(float* p, float v){ __hip_atomic_store(p, v, __ATOMIC_RELAXED, __HIP_MEMORY_SCOPE_AGENT); }
DEV int   aload_i(const int* p){ return __hip_atomic_load(p, __ATOMIC_RELAXED, __HIP_MEMORY_SCOPE_AGENT); }
DEV void  astore_i(int* p, int v){ __hip_atomic_store(p, v, __ATOMIC_RELAXED, __HIP_MEMORY_SCOPE_AGENT); }
DEV unsigned long long aload_u64(const unsigned long long* p){ return __hip_atomic_load(p, __ATOMIC_RELAXED, __HIP_MEMORY_SCOPE_AGENT); }
DEV void astore_u64(unsigned long long* p, unsigned long long v){ __hip_atomic_store(p, v, __ATOMIC_RELAXED, __HIP_MEMORY_SCOPE_AGENT); }

typedef short bfrag8 __attribute__((ext_vector_type(8)));
typedef float ffrag4 __attribute__((ext_vector_type(4)));

// swizzled element offset into a [32 rows][64 cols] bf16 h-tile
DEV int off_h(int row, int col){
  return row*64 + ((((col >> 3) ^ (row & 7)) << 3) | (col & 7));
}

DEV short bfbits(float v){ __hip_bfloat16 b = f2bf(v); return *reinterpret_cast<short*>(&b); }

// ---------------------------------------------------------------- init (flags + CSR counters only)
__global__ void k_init(int* bcnt, int* bfill, int* flagA, unsigned long long* pbB){
  int i = blockIdx.x*256 + threadIdx.x;
  if (i < Tt*CHK*16){ flagA[i] = 0; pbB[i] = 0ull; }
  if (i < Tt*NB){ bcnt[i] = 0; bfill[i] = 0; }
}

// ---------------------------------------------------------------- stage 1: block-aggregated bucket histogram
__global__ __launch_bounds__(256) void k_bcnt(const int* __restrict__ ei, int* __restrict__ bcnt){
  __shared__ int h[NB];
  const int b = blockIdx.x;                 // 1416 = 8*177
  const int w = (b & 7)*177 + (b >> 3);
  const int t = w / BPT, ch = w - t*BPT;
  const int e0 = ch*EPB;
  const int tid = threadIdx.x;
  for (int i = tid; i < NB; i += 256) h[i] = 0;
  __syncthreads();
  #pragma unroll
  for (int i = 0; i < 32; ++i){
    int e = e0 + i*256 + tid;
    if (e < Ee){
      int r = ei[(size_t)(t*2)*Ee + e];
      atomicAdd(&h[r >> 7], 1);
    }
  }
  __syncthreads();
  for (int i = tid; i < NB; i += 256){
    int c = h[i];
    if (c > 0) atomicAdd(&bcnt[t*NB + i], c);
  }
}

// ---------------------------------------------------------------- stage 2: per-t exclusive scan of bucket counts
__global__ __launch_bounds__(256) void k_bscan(const int* __restrict__ bcnt, int* __restrict__ rpb){
  int t = blockIdx.x, tid = threadIdx.x;
  __shared__ int ps[256];
  int v = (tid < NB) ? bcnt[t*NB + tid] : 0;
  ps[tid] = v;
  __syncthreads();
  for (int o = 1; o < 256; o <<= 1){
    int x = (tid >= o) ? ps[tid-o] : 0;
    __syncthreads();
    ps[tid] += x;
    __syncthreads();
  }
  if (tid < NB) rpb[t*(NB+1) + tid] = ps[tid] - v;
  if (tid == 255) rpb[t*(NB+1) + NB] = ps[NB-1];
}

// ---------------------------------------------------------------- stage 3: partition edges into buckets (block-aggregated reservations)
__global__ __launch_bounds__(256) void k_part2(const int* __restrict__ ei, const int* __restrict__ rpb,
    int* __restrict__ bfill, unsigned* __restrict__ pair){
  __shared__ int hcnt[NB];
  __shared__ int hbase[NB];
  const int b = blockIdx.x;                 // 1416 = 8*177
  const int w = (b & 7)*177 + (b >> 3);
  const int t = w / BPT, ch = w - t*BPT;
  const int e0 = ch*EPB;
  const int tid = threadIdx.x;
  for (int i = tid; i < NB; i += 256) hcnt[i] = 0;
  __syncthreads();
  unsigned key[32];
  #pragma unroll
  for (int i = 0; i < 32; ++i){
    int e = e0 + i*256 + tid;
    unsigned k = 0xFFFFFFFFu;
    if (e < Ee){
      int r = ei[(size_t)(t*2)*Ee + e];
      int c = ei[(size_t)(t*2+1)*Ee + e];
      k = ((unsigned)r << 16) | (unsigned)c;
      atomicAdd(&hcnt[r >> 7], 1);
    }
    key[i] = k;
  }
  __syncthreads();
  for (int i = tid; i < NB; i += 256){
    int cnt = hcnt[i];
    int base = (cnt > 0) ? atomicAdd(&bfill[t*NB + i], cnt) : 0;
    hbase[i] = rpb[t*(NB+1) + i] + base;
  }
  __syncthreads();
  for (int i = tid; i < NB; i += 256) hcnt[i] = 0;
  __syncthreads();
  #pragma unroll
  for (int i = 0; i < 32; ++i){
    unsigned k = key[i];
    if (k != 0xFFFFFFFFu){
      int r = (int)(k >> 16);
      int bk = r >> 7;
      int pos = atomicAdd(&hcnt[bk], 1);
      pair[(size_t)t*Ee + hbase[bk] + pos] = ((unsigned)(r & 127) << 16) | (k & 0xFFFFu);
    }
  }
}

// ---------------------------------------------------------------- stage 4: per-bucket LDS counting sort -> col16, rp, dinv
__global__ __launch_bounds__(256) void k_csr2(const int* __restrict__ rpb, const unsigned* __restrict__ pair,
    unsigned short* __restrict__ col16, int* __restrict__ rp, float* __restrict__ dinv){
  __shared__ unsigned short cols_s[9216];
  __shared__ int lcnt[128], lfill[128];
  __shared__ int ps[256];
  const int blk = blockIdx.x;               // Tt*NB
  const int t = blk / NB, bk = blk - t*NB;
  const int r0 = bk << 7;
  const int nr = (r0 + 128 <= Mn) ? 128 : (Mn - r0);
  const int base = rpb[t*(NB+1) + bk];
  const int cnt  = rpb[t*(NB+1) + bk + 1] - base;
  const int tid = threadIdx.x;
  if (tid < 128) lcnt[tid] = 0;
  __syncthreads();
  for (int i = tid; i < cnt; i += 256){
    unsigned v = pair[(size_t)t*Ee + base + i];
    atomicAdd(&lcnt[v >> 16], 1);
  }
  __syncthreads();
  int v2 = (tid < 128) ? lcnt[tid] : 0;
  ps[tid] = v2;
  __syncthreads();
  for (int o = 1; o < 128; o <<= 1){
    int x = (tid >= o) ? ps[tid-o] : 0;
    __syncthreads();
    ps[tid] += x;
    __syncthreads();
  }
  if (tid < 128){
    int excl = ps[tid] - v2;
    lfill[tid] = excl;
    if (tid < nr){
      rp[t*(Mn+1) + r0 + tid] = base + excl;
      dinv[t*Mn + r0 + tid] = (v2 > 0) ? rsqrtf((float)v2) : 0.f;  // folded k_dinv
    }
  }
  if (bk == NB-1 && tid == 0) rp[t*(Mn+1) + Mn] = base + cnt;
  __syncthreads();
  for (int i = tid; i < cnt; i += 256){
    unsigned v = pair[(size_t)t*Ee + base + i];
    int pos = atomicAdd(&lfill[v >> 16], 1);
    cols_s[pos] = (unsigned short)(v & 0xFFFFu);
  }
  __syncthreads();
  for (int i = tid; i < cnt; i += 256)
    col16[(size_t)t*Ee + base + i] = cols_s[i];
}

// ---------------------------------------------------------------- degree-balanced row permutation per (t,chunk)
// Counting-sort of the chunk's rows by degree so pitall's waves get 64
// near-equal-degree rows (kills gather wave-divergence: iterations = mean
// degree ~32 instead of max-of-64 ~47). Per-row math/storage unchanged.
__global__ __launch_bounds__(1024) void k_perm(const int* __restrict__ rp, int* __restrict__ prow){
  __shared__ int hist[256], hbase[256], ps[256];
  const int b = blockIdx.x;                 // Tt*CHK
  const int t = b / CHK, ch = b - t*CHK;
  const int r0 = ch*RC;
  const int r1 = (r0 + RC < Mn) ? r0 + RC : Mn;
  const int n = r1 - r0;
  const int tid = threadIdx.x;
  if (tid < 256) hist[tid] = 0;
  __syncthreads();
  const int* rpt = rp + t*(Mn+1);
  int d0 = -1, d1 = -1;
  if (tid < n){ int m = r0 + tid; d0 = min(rpt[m+1]-rpt[m], 255); atomicAdd(&hist[d0], 1); }
  if (1024 + tid < n){ int m = r0 + 1024 + tid; d1 = min(rpt[m+1]-rpt[m], 255); atomicAdd(&hist[d1], 1); }
  __syncthreads();
  if (tid < 256) ps[tid] = hist[tid];
  __syncthreads();
  for (int o = 1; o < 256; o <<= 1){
    int x = (tid >= o && tid < 256) ? ps[tid-o] : 0;
    __syncthreads();
    if (tid < 256) ps[tid] += x;
    __syncthreads();
  }
  if (tid < 256){ hbase[tid] = ps[tid] - hist[tid]; hist[tid] = 0; }
  __syncthreads();
  if (d0 >= 0){ int pos = hbase[d0] + atomicAdd(&hist[d0], 1); prow[(size_t)b*RC + pos] = r0 + tid; }
  if (d1 >= 0){ int pos = hbase[d1] + atomicAdd(&hist[d1], 1); prow[(size_t)b*RC + pos] = r0 + 1024 + tid; }
}

// ---------------------------------------------------------------- GRU layer 0 (both dirs) via MFMA, writes y0 (T,M,128) bf16
__global__ __launch_bounds__(256) void k_gru0(
    const float* __restrict__ nf, const float* __restrict__ Wih, const float* __restrict__ Whh,
    const float* __restrict__ bih, const float* __restrict__ bhh, __hip_bfloat16* __restrict__ y0)
{
  __shared__ __hip_bfloat16 xp[Tt*32*32];   // [t][row][k]: cols 0-15 x_hi, 16-31 x_lo (24.6 KB)
  __shared__ __hip_bfloat16 h_hi[32*64];    // swizzled (4 KB)
  __shared__ __hip_bfloat16 h_lo[32*64];    // swizzled (4 KB)
  const int tid = threadIdx.x;
  const int m0  = blockIdx.x*32;
  const int lane = tid & 63, wv = tid >> 6;
  const int lr = lane & 15, lq = lane >> 4;
  for (int idx = tid; idx < Tt*32*CIN; idx += 256){
    int t = idx >> 9; int row = (idx >> 4) & 31; int k = idx & 15;
    int m = m0 + row;
    float v = (m < Mn) ? nf[((size_t)t*Mn + m)*CIN + k] : 0.f;
    __hip_bfloat16 hi = f2bf(v);
    xp[(t*32 + row)*32 + k]      = hi;
    xp[(t*32 + row)*32 + 16 + k] = f2bf(v - bf2f(hi));
  }
  for (int d = 0; d < 2; ++d){
    bfrag8 Bh[3][2], Bx[3];
    float b_r, b_z, b_in, b_hn;
    {
      const float* Wh = Whh + (size_t)d*Gg*Hh;
      const float* Wx = Wih + (size_t)d*Gg*CIN;
      #pragma unroll
      for (int c = 0; c < 3; ++c){
        int g = (wv + 4*c)*16 + lr;
        #pragma unroll
        for (int ks = 0; ks < 2; ++ks){
          bfrag8 f;
          #pragma unroll
          for (int r = 0; r < 8; ++r) f[r] = bfbits(Wh[(size_t)g*Hh + ks*32 + lq*8 + r]);
          Bh[c][ks] = f;
        }
        bfrag8 fx;
        #pragma unroll
        for (int r = 0; r < 8; ++r) fx[r] = bfbits(Wx[(size_t)g*CIN + ((lq*8 + r) & 15)]);
        Bx[c] = fx;
      }
      int j = wv*16 + lr;
      b_r  = bih[d*Gg + j]        + bhh[d*Gg + j];
      b_z  = bih[d*Gg + Hh + j]   + bhh[d*Gg + Hh + j];
      b_in = bih[d*Gg + 2*Hh + j];
      b_hn = bhh[d*Gg + 2*Hh + j];
    }
    float hreg[8];
    #pragma unroll
    for (int q = 0; q < 8; ++q) hreg[q] = 0.f;
    for (int i = tid; i < 32*64; i += 256){ h_hi[i] = f2bf(0.f); h_lo[i] = f2bf(0.f); }
    __syncthreads();
    for (int step = 0; step < Tt; ++step){
      int t = d ? (Tt-1-step) : step;
      bfrag8 xa[2], hhf[2][2], hlf[2][2];
      #pragma unroll
      for (int rt = 0; rt < 2; ++rt){
        int row = rt*16 + lr;
        xa[rt] = *(const bfrag8*)&xp[(t*32 + row)*32 + lq*8];
        #pragma unroll
        for (int ks = 0; ks < 2; ++ks){
          int e = off_h(row, ks*32 + lq*8);
          hhf[rt][ks] = *(const bfrag8*)&h_hi[e];
          hlf[rt][ks] = *(const bfrag8*)&h_lo[e];
        }
      }
      ffrag4 Cr[2], Cz[2], Cai[2], Cah[2];
      #pragma unroll
      for (int rt = 0; rt < 2; ++rt){
        ffrag4 z4 = (ffrag4){0.f,0.f,0.f,0.f};
        Cr[rt]  = __builtin_amdgcn_mfma_f32_16x16x32_bf16(xa[rt], Bx[0], z4, 0,0,0);
        Cz[rt]  = __builtin_amdgcn_mfma_f32_16x16x32_bf16(xa[rt], Bx[1], z4, 0,0,0);
        Cai[rt] = __builtin_amdgcn_mfma_f32_16x16x32_bf16(xa[rt], Bx[2], z4, 0,0,0);
        Cah[rt] = z4;
        #pragma unroll
        for (int ks = 0; ks < 2; ++ks){
          Cr[rt]  = __builtin_amdgcn_mfma_f32_16x16x32_bf16(hhf[rt][ks], Bh[0][ks], Cr[rt], 0,0,0);
          Cr[rt]  = __builtin_amdgcn_mfma_f32_16x16x32_bf16(hlf[rt][ks], Bh[0][ks], Cr[rt], 0,0,0);
          Cz[rt]  = __builtin_amdgcn_mfma_f32_16x16x32_bf16(hhf[rt][ks], Bh[1][ks], Cz[rt], 0,0,0);
          Cz[rt]  = __builtin_amdgcn_mfma_f32_16x16x32_bf16(hlf[rt][ks], Bh[1][ks], Cz[rt], 0,0,0);
          Cah[rt] = __builtin_amdgcn_mfma_f32_16x16x32_bf16(hhf[rt][ks], Bh[2][ks], Cah[rt], 0,0,0);
          Cah[rt] = __builtin_amdgcn_mfma_f32_16x16x32_bf16(hlf[rt][ks], Bh[2][ks], Cah[rt], 0,0,0);
        }
      }
      __syncthreads();
      #pragma unroll
      for (int rt = 0; rt < 2; ++rt){
        #pragma unroll
        for (int q = 0; q < 4; ++q){
          float r = sigm(Cr[rt][q] + b_r);
          float z = sigm(Cz[rt][q] + b_z);
          float n = tanh_f((Cai[rt][q] + b_in) + r*(Cah[rt][q] + b_hn));
          float h = (1.f - z)*n + z*hreg[rt*4+q];
          hreg[rt*4+q] = h;
          __hip_bfloat16 hi = f2bf(h);
          int e = off_h(rt*16 + lq*4 + q, wv*16 + lr);
          h_hi[e] = hi;
          h_lo[e] = f2bf(h - bf2f(hi));
        }
      }
      __syncthreads();
      {
        int row = tid >> 3, cg = tid & 7;
        int m = m0 + row;
        if (m < Mn){
          float4 v = *(const float4*)&h_hi[off_h(row, cg*8)];
          *(float4*)&y0[((size_t)t*Mn + m)*C2 + d*Hh + cg*8] = v;
        }
      }
    }
    __syncthreads();
  }
}

// ---------------------------------------------------------------- convert layer-1 reverse Wih to bf16
__global__ void k_wcvt(const float* __restrict__ W, __hip_bfloat16* __restrict__ Wbf){
  int i = blockIdx.x*256 + threadIdx.x;
  if (i < Gg*C2) Wbf[i] = f2bf(W[i]);
}

// ---------------------------------------------------------------- GRU layer 1 (reverse) via MFMA with FUSED input projection
__global__ __launch_bounds__(256) void k_gru1r(const __hip_bfloat16* __restrict__ y0,
    const __hip_bfloat16* __restrict__ Wbf, const float* __restrict__ Whh,
    const float* __restrict__ bih, const float* __restrict__ bhh,
    const float* __restrict__ lns, const float* __restrict__ lnb,
    __hip_bfloat16* __restrict__ xbt)
{
  __shared__ __hip_bfloat16 h_hi[32*64];    // swizzled (4 KB)
  __shared__ __hip_bfloat16 h_lo[32*64];
  __shared__ float h_f32[32*72];            // exact f32 h for LayerNorm (9.2 KB)
  __shared__ float sc[Hh], bs[Hh];
  const int tid = threadIdx.x;
  const int seg = blockIdx.x;
  const int m0  = seg*32;
  const int lane = tid & 63, wv = tid >> 6;
  const int lr = lane & 15, lq = lane >> 4;
  bfrag8 Bh[3][2];
  #pragma unroll
  for (int c = 0; c < 3; ++c){
    int g = (wv + 4*c)*16 + lr;
    #pragma unroll
    for (int ks = 0; ks < 2; ++ks){
      bfrag8 f;
      #pragma unroll
      for (int r = 0; r < 8; ++r) f[r] = bfbits(Whh[(size_t)g*Hh + ks*32 + lq*8 + r]);
      Bh[c][ks] = f;
    }
  }
  bfrag8 Bp[3][4];
  #pragma unroll
  for (int c = 0; c < 3; ++c){
    int g = (wv + 4*c)*16 + lr;
    #pragma unroll
    for (int ks = 0; ks < 4; ++ks)
      Bp[c][ks] = *(const bfrag8*)(Wbf + (size_t)g*C2 + ks*32 + lq*8);
  }
  float b_r, b_z, b_in, b_hn;
  {
    int j = wv*16 + lr;
    b_r  = bih[j]      + bhh[j];
    b_z  = bih[Hh+j]   + bhh[Hh+j];
    b_in = bih[2*Hh+j];
    b_hn = bhh[2*Hh+j];
  }
  if (tid < Hh){ sc[tid] = lns[tid]; bs[tid] = lnb[tid]; }
  float hreg[8];
  #pragma unroll
  for (int q = 0; q < 8; ++q) hreg[q] = 0.f;
  for (int i = tid; i < 32*64; i += 256){ h_hi[i] = f2bf(0.f); h_lo[i] = f2bf(0.f); }
  __syncthreads();
  for (int step = 0; step < Tt; ++step){
    int t = Tt-1-step;
    const __hip_bfloat16* yb = y0 + (size_t)t*Mn*C2;
    ffrag4 Cr[2], Cz[2], Cai[2], Cah[2];
    #pragma unroll
    for (int rt = 0; rt < 2; ++rt){
      ffrag4 z4 = (ffrag4){0.f,0.f,0.f,0.f};
      Cr[rt] = z4; Cz[rt] = z4; Cai[rt] = z4; Cah[rt] = z4;
    }
    #pragma unroll
    for (int ks = 0; ks < 4; ++ks){
      const int ko = ks*32 + lq*8;
      bfrag8 a0 = *(const bfrag8*)(yb + (size_t)(m0 + lr     )*C2 + ko);
      bfrag8 a1 = *(const bfrag8*)(yb + (size_t)(m0 + 16 + lr)*C2 + ko);
      Cr[0]  = __builtin_amdgcn_mfma_f32_16x16x32_bf16(a0, Bp[0][ks], Cr[0], 0,0,0);
      Cr[1]  = __builtin_amdgcn_mfma_f32_16x16x32_bf16(a1, Bp[0][ks], Cr[1], 0,0,0);
      Cz[0]  = __builtin_amdgcn_mfma_f32_16x16x32_bf16(a0, Bp[1][ks], Cz[0], 0,0,0);
      Cz[1]  = __builtin_amdgcn_mfma_f32_16x16x32_bf16(a1, Bp[1][ks], Cz[1], 0,0,0);
      Cai[0] = __builtin_amdgcn_mfma_f32_16x16x32_bf16(a0, Bp[2][ks], Cai[0], 0,0,0);
      Cai[1] = __builtin_amdgcn_mfma_f32_16x16x32_bf16(a1, Bp[2][ks], Cai[1], 0,0,0);
    }
    bfrag8 hhf[2][2], hlf[2][2];
    #pragma unroll
    for (int rt = 0; rt < 2; ++rt){
      int row = rt*16 + lr;
      #pragma unroll
      for (int ks = 0; ks < 2; ++ks){
        int e = off_h(row, ks*32 + lq*8);
        hhf[rt][ks] = *(const bfrag8*)&h_hi[e];
        hlf[rt][ks] = *(const bfrag8*)&h_lo[e];
      }
    }
    #pragma unroll
    for (int rt = 0; rt < 2; ++rt){
      #pragma unroll
      for (int ks = 0; ks < 2; ++ks){
        Cr[rt]  = __builtin_amdgcn_mfma_f32_16x16x32_bf16(hhf[rt][ks], Bh[0][ks], Cr[rt], 0,0,0);
        Cr[rt]  = __builtin_amdgcn_mfma_f32_16x16x32_bf16(hlf[rt][ks], Bh[0][ks], Cr[rt], 0,0,0);
        Cz[rt]  = __builtin_amdgcn_mfma_f32_16x16x32_bf16(hhf[rt][ks], Bh[1][ks], Cz[rt], 0,0,0);
        Cz[rt]  = __builtin_amdgcn_mfma_f32_16x16x32_bf16(hlf[rt][ks], Bh[1][ks], Cz[rt], 0,0,0);
        Cah[rt] = __builtin_amdgcn_mfma_f32_16x16x32_bf16(hhf[rt][ks], Bh[2][ks], Cah[rt], 0,0,0);
        Cah[rt] = __builtin_amdgcn_mfma_f32_16x16x32_bf16(hlf[rt][ks], Bh[2][ks], Cah[rt], 0,0,0);
      }
    }
    __syncthreads();
    #pragma unroll
    for (int rt = 0; rt < 2; ++rt){
      #pragma unroll
      for (int q = 0; q < 4; ++q){
        float r = sigm(Cr[rt][q] + b_r);
        float z = sigm(Cz[rt][q] + b_z);
        float n = tanh_f((Cai[rt][q] + b_in) + r*(Cah[rt][q] + b_hn));
        float h = (1.f - z)*n + z*hreg[rt*4+q];
        hreg[rt*4+q] = h;
        __hip_bfloat16 hi = f2bf(h);
        int row = rt*16 + lq*4 + q;
        int e = off_h(row, wv*16 + lr);
        h_hi[e] = hi;
        h_lo[e] = f2bf(h - bf2f(hi));
        h_f32[row*72 + wv*16 + lr] = h;
      }
    }
    __syncthreads();
    {
      int row = tid >> 3, l = tid & 7;
      float4 v0 = *(const float4*)&h_f32[row*72 + l*8];
      float4 v1 = *(const float4*)&h_f32[row*72 + l*8 + 4];
      float vals[8] = {v0.x, v0.y, v0.z, v0.w, v1.x, v1.y, v1.z, v1.w};
      float s1 = 0.f, s2 = 0.f;
      #pragma unroll
      for (int q = 0; q < 8; ++q){ s1 += vals[q]; s2 += vals[q]*vals[q]; }
      #pragma unroll
      for (int off = 1; off <= 4; off <<= 1){ s1 += __shfl_xor(s1, off); s2 += __shfl_xor(s2, off); }
      float mu  = s1 * (1.f/64.f);
      float var = s2 * (1.f/64.f) - mu*mu;
      float rs  = rsqrtf(var + 1e-5f);
      int m = m0 + row;
      if (m < Mn){
        __hip_bfloat16 ob[8];
        #pragma unroll
        for (int q = 0; q < 8; ++q){ int j = l*8 + q; ob[q] = f2bf((vals[q]-mu)*rs*sc[j] + bs[j]); }
        *(float4*)&xbt[((size_t)t*Mn + m)*Hh + l*8] = *(float4*)ob;
      }
    }
    __syncthreads();
  }
}

// ---------------------------------------------------------------- fused power iteration (R5 sync structure + degree-balanced rows)
// Split into round ranges [rA, rB] across two launches (barrier state is all
// in global memory, so the split is free) -- diagnostic + same semantics.
__global__ __launch_bounds__(1024) void k_pitall(const int* __restrict__ rp,
    const unsigned short* __restrict__ col, float* __restrict__ urb,
    int* __restrict__ flagA, unsigned long long* __restrict__ pbB,
    float* __restrict__ lamc, const int* __restrict__ prow, int rA, int rB)
{
  __shared__ alignas(16) float u_s[Mn];     // 120000 B
  __shared__ float redw[16];
  __shared__ float s_nrm;
  __shared__ int s_goA, s_goB;
  const int b = blockIdx.x;                 // Tt*CHK = 252
  const int t = b / CHK, ch = b - t*CHK;
  const int r0 = ch*RC;
  const int r1 = (r0 + RC < Mn) ? r0 + RC : Mn;
  const int n = r1 - r0;
  const int tid = threadIdx.x;
  const int lane = tid & 63;
  const int wv   = tid >> 6;                // wave id 0..15
  const unsigned short* cp = col + (size_t)t*Ee;
  const int fS = t*CHK*16;                  // flagA slots: u32, 64B apart
  const int pB = t*CHK*16;                  // pbB slots: u64, per block 2 parity x 64B
  // degree-balanced row assignment (permutation within chunk)
  const int* pr = prow + (size_t)b*RC;
  const int rowA = (tid < n)        ? pr[tid]        : -1;
  const int rowB = (1024 + tid < n) ? pr[1024 + tid] : -1;
  int rb0 = 0, re0 = 0, rb1 = 0, re1 = 0;
  {
    const int* rpt = rp + t*(Mn+1);
    if (rowA >= 0){ rb0 = rpt[rowA]; re0 = rpt[rowA+1]; }
    if (rowB >= 0){ rb1 = rpt[rowB]; re1 = rpt[rowB+1]; }
  }
  if (tid == 0){ s_nrm = 1.0f; s_goA = 0; s_goB = 0; }
  __syncthreads();
  for (int r = rA; r <= rB; ++r){
    const int fin = (r == NRND);
    if (r == 1){
      for (int i = tid; i < Mn; i += 1024) u_s[i] = 0.005773502691896258f;
    } else {
      const int rr = r - 1;
      const float4* u4 = (const float4*)(urb + (size_t)rr*(Tt*Mn) + (size_t)t*Mn);
      float4* s4 = (float4*)u_s;
      if (wv == 0){
        const bool mine = lane < CHK;
        for (;;){ int v = mine ? aload_i(&flagA[fS + lane*16]) : 0x7FFFFFFF;
                  if (__all(v >= rr)) break; __builtin_amdgcn_s_sleep(4); }
        if (lane == 0) __hip_atomic_store(&s_goA, rr, __ATOMIC_RELAXED, __HIP_MEMORY_SCOPE_WORKGROUP);
      } else {
        while (__hip_atomic_load(&s_goA, __ATOMIC_RELAXED, __HIP_MEMORY_SCOPE_WORKGROUP) < rr)
          __builtin_amdgcn_s_sleep(2);
      }
      asm volatile("" ::: "memory");
      for (int i = tid; i < NF4A; i += 1024){
        int idx = (i >> 8)*360 + (i & 255);
        s4[idx] = u4[idx];
      }
      unsigned long long pv = 0;
      if (wv == 0){
        const bool mine = lane < CHK;
        for (;;){ pv = mine ? aload_u64(&pbB[(size_t)(pB + lane*16) + (rr & 1)*8])
                            : ((unsigned long long)rr << 32);
                  if (__all((int)(pv >> 32) == rr)) break; __builtin_amdgcn_s_sleep(4); }
        if (lane == 0) __hip_atomic_store(&s_goB, rr, __ATOMIC_RELAXED, __HIP_MEMORY_SCOPE_WORKGROUP);
      } else {
        while (__hip_atomic_load(&s_goB, __ATOMIC_RELAXED, __HIP_MEMORY_SCOPE_WORKGROUP) < rr)
          __builtin_amdgcn_s_sleep(2);
      }
      asm volatile("" ::: "memory");
      for (int i = tid; i < NF4B; i += 1024){
        int ck = i/104, off = i - ck*104;
        int idx = ck*360 + 256 + off;
        s4[idx] = u4[idx];
      }
      if (wv == 0){
        float p = (lane < CHK) ? __uint_as_float((unsigned)pv) : 0.f;
        #pragma unroll
        for (int o2 = 1; o2 < 32; o2 <<= 1) p += __shfl_xor(p, o2);
        if (tid == 0) s_nrm = p;
      }
    }
    __syncthreads();
    const float inv_s = fin ? 1.f : 1.f/(sqrtf(s_nrm) + 1e-12f);
    float* u_ot = urb + (size_t)r*(Tt*Mn);
    float local = 0.f;
    if (rowA >= 0){
      float s = 0.f;
      int i = rb0;
      for (; i < re0 && (i & 3); ++i) s += u_s[cp[i]];
      for (; i + 4 <= re0; i += 4){
        ushort4 c4 = *(const ushort4*)(cp + i);
        s += (u_s[c4.x] + u_s[c4.y]) + (u_s[c4.z] + u_s[c4.w]);
      }
      for (; i < re0; ++i) s += u_s[cp[i]];
      float uv = u_s[rowA];
      float wv2 = (float)(re0 - rb0)*uv - s;
      if (!fin){ float o = inv_s*wv2; astore_f(&u_ot[t*Mn + rowA], o); local += o*o; }
      else local += uv*wv2;
    }
    asm volatile("s_waitcnt vmcnt(0)" ::: "memory");
    __syncthreads();
    if (tid == 0) astore_i(&flagA[fS + ch*16], r);
    if (rowB >= 0){
      float s = 0.f;
      int i = rb1;
      for (; i < re1 && (i & 3); ++i) s += u_s[cp[i]];
      for (; i + 4 <= re1; i += 4){
        ushort4 c4 = *(const ushort4*)(cp + i);
        s += (u_s[c4.x] + u_s[c4.y]) + (u_s[c4.z] + u_s[c4.w]);
      }
      for (; i < re1; ++i) s += u_s[cp[i]];
      float uv = u_s[rowB];
      float wv2 = (float)(re1 - rb1)*uv - s;
      if (!fin){ float o = inv_s*wv2; astore_f(&u_ot[t*Mn + rowB], o); local += o*o; }
      else local += uv*wv2;
    }
    #pragma unroll
    for (int o2 = 1; o2 < 64; o2 <<= 1) local += __shfl_xor(local, o2);
    if ((tid & 63) == 0) redw[tid >> 6] = local;
    asm volatile("s_waitcnt vmcnt(0)" ::: "memory");
    __syncthreads();
    if (tid < 64){
      float tot = (tid < 16) ? redw[tid] : 0.f;
      #pragma unroll
      for (int o2 = 1; o2 < 16; o2 <<= 1) tot += __shfl_xor(tot, o2);
      if (tid == 0){
        unsigned long long out = ((unsigned long long)r << 32)
                               | (unsigned long long)__float_as_uint(tot);
        astore_u64(&pbB[(size_t)(pB + ch*16) + (r & 1)*8], out);
      }
    }
  }
  // folded lamfin: only the final-range launch, ch==0
  if (rB == NRND && ch == 0 && tid < 64){
    const bool mine = lane < CHK;
    unsigned long long pv = 0;
    for (;;){ pv = mine ? aload_u64(&pbB[(size_t)(pB + lane*16) + (NRND & 1)*8])
                        : ((unsigned long long)NRND << 32);
              if (__all((int)(pv >> 32) == NRND)) break; __builtin_amdgcn_s_sleep(4); }
    float p = mine ? __uint_as_float((unsigned)pv) : 0.f;
    #pragma unroll
    for (int o2 = 1; o2 < 32; o2 <<= 1) p += __shfl_xor(p, o2);
    if (tid == 0){
      float nn = sqrtf(s_nrm) + 1e-12f;
      float lam = p / (nn*nn);
      lamc[2*t+0] = -2.f/lam;
      lamc[2*t+1] =  2.f/lam - 1.f;
    }
  }
}

// ---------------------------------------------------------------- Chebyshev SpMM (wave per row, lane = channel, XCD-swizzled)
__global__ __launch_bounds__(256) void k_cheb(const __hip_bfloat16* __restrict__ xin,
    const __hip_bfloat16* __restrict__ xb0, __hip_bfloat16* __restrict__ outp,
    const int* __restrict__ rp, const unsigned short* __restrict__ col,
    const float* __restrict__ dinv, const float* __restrict__ lamc, float s1, float s2)
{
  const int blk = blockIdx.x;               // 90000 = 8*11250
  const int w = (blk & 7)*11250 + (blk >> 3);
  const int gw = w*4 + (threadIdx.x >> 6);
  const int lane = threadIdx.x & 63;
  int t = gw / Mn, m = gw - t*Mn;
  float coef = lamc[2*t], diag = lamc[2*t+1];
  const __hip_bfloat16* xt = xin + (size_t)t*Mn*Hh;
  const float* dv = dinv + t*Mn;
  float acc = diag * bf2f(xt[(size_t)m*Hh + lane]);
  float cdm = coef * dv[m];
  int bgn = rp[t*(Mn+1)+m], end = rp[t*(Mn+1)+m+1];
  const unsigned short* cp = col + (size_t)t*Ee;
  int i = bgn;
  for (; i < end && (i & 3); ++i){ int c = cp[i]; acc += (cdm*dv[c])*bf2f(xt[(size_t)c*Hh + lane]); }
  for (; i + 4 <= end; i += 4){
    ushort4 c4 = *(const ushort4*)(cp + i);
    float w0 = cdm*dv[c4.x], w1 = cdm*dv[c4.y], w2 = cdm*dv[c4.z], w3 = cdm*dv[c4.w];
    acc += w0*bf2f(xt[(size_t)c4.x*Hh + lane]);
    acc += w1*bf2f(xt[(size_t)c4.y*Hh + lane]);
    acc += w2*bf2f(xt[(size_t)c4.z*Hh + lane]);
    acc += w3*bf2f(xt[(size_t)c4.w*Hh + lane]);
  }
  for (; i < end; ++i){ int c = cp[i]; acc += (cdm*dv[c])*bf2f(xt[(size_t)c*Hh + lane]); }
  float o = s1*acc;
  if (s2 != 0.f) o += s2*bf2f(xb0[(size_t)gw*Hh + lane]);
  outp[(size_t)gw*Hh + lane] = f2bf(o);
}

// ---------------------------------------------------------------- fold cheb_W into conv_W
__global__ void k_ww(const float* __restrict__ chebW, const float* __restrict__ chebb,
    const float* __restrict__ convW, const float* __restrict__ convb, float* __restrict__ WW, float* __restrict__ c0)
{
  int idx = blockIdx.x*256 + threadIdx.x;
  if (idx < 3*Tt*Hh*Oo){
    int oc = idx % Oo; int j = (idx/Oo) % Hh; int t = (idx/(Oo*Hh)) % Tt; int i = idx/(Oo*Hh*Tt);
    const float* cw = chebW + ((size_t)i*Hh + j)*HC + (HC-KW);
    const float* vw = convW + ((size_t)oc*Tt + t)*KW;
    float s = 0.f;
    for (int k = 0; k < KW; ++k) s += cw[k]*vw[k];
    WW[idx] = s;
  }
  if (blockIdx.x == 0 && threadIdx.x < Oo){
    int oc = threadIdx.x;
    float s = convb[oc];
    for (int t = 0; t < Tt; ++t){
      const float* vw = convW + ((size_t)oc*Tt + t)*KW;
      for (int k = 0; k < KW; ++k) s += chebb[(HC-KW)+k]*vw[k];
    }
    c0[oc] = s;
  }
}

// ---------------------------------------------------------------- fused cheb-GEMM + temporal conv + sigmoid
__global__ __launch_bounds__(256) void k_final(const __hip_bfloat16* __restrict__ tx0,
    const __hip_bfloat16* __restrict__ tx1, const __hip_bfloat16* __restrict__ tx2,
    const float* __restrict__ WW, const float* __restrict__ c0, float* __restrict__ outp)
{
  __shared__ float xs[64][65];
  __shared__ float ww[64][12];
  const int tid = threadIdx.x;
  const int n0 = blockIdx.x*64;
  const int n = tid & 63, ob = (tid >> 6)*3;
  float acc[3] = {0.f, 0.f, 0.f};
  for (int it = 0; it < 3*Tt; ++it){
    int ii = it / Tt, t = it % Tt;
    const __hip_bfloat16* tx = (ii == 0) ? tx0 : (ii == 1) ? tx1 : tx2;
    __syncthreads();
    for (int idx = tid; idx < 64*64; idx += 256){
      int mm = idx >> 6, j = idx & 63;
      int m = n0 + mm;
      xs[mm][j] = (m < Mn) ? bf2f(tx[((size_t)t*Mn + m)*Hh + j]) : 0.f;
    }
    for (int idx = tid; idx < 64*Oo; idx += 256)
      ((float*)ww)[idx] = WW[((size_t)(ii*Tt + t)*Hh)*Oo + idx];
    __syncthreads();
    #pragma unroll 8
    for (int j = 0; j < 64; ++j){
      float x = xs[n][j];
      acc[0] += x*ww[j][ob+0];
      acc[1] += x*ww[j][ob+1];
      acc[2] += x*ww[j][ob+2];
    }
  }
  int m = n0 + n;
  if (m < Mn){
    #pragma unroll
    for (int q = 0; q < 3; ++q) outp[(size_t)m*Oo + ob + q] = sigm(acc[q] + c0[ob+q]);
  }
}

// ================================================================ host
extern "C" void kernel_launch(void* const* d_in, const int* in_sizes, int n_in,
                              void* d_out, int out_size, void* d_ws, size_t ws_size,
                              hipStream_t stream)
{
  const float* nf    = (const float*)d_in[0];
  const int*   ei    = (const int*)d_in[1];
  const float* Wih0  = (const float*)d_in[2];
  const float* Whh0  = (const float*)d_in[3];
  const float* bih0  = (const float*)d_in[4];
  const float* bhh0  = (const float*)d_in[5];
  const float* Wih1  = (const float*)d_in[6];
  const float* Whh1  = (const float*)d_in[7];
  const float* bih1  = (const float*)d_in[8];
  const float* bhh1  = (const float*)d_in[9];
  const float* lns   = (const float*)d_in[10];
  const float* lnb   = (const float*)d_in[11];
  const float* chebW = (const float*)d_in[12];
  const float* chebb = (const float*)d_in[13];
  const float* convW = (const float*)d_in[14];
  const float* convb = (const float*)d_in[15];
  float* outp = (float*)d_out;

  char* base = (char*)d_ws;
  size_t off = 0;
  auto alloc = [&](size_t bytes)->char*{ char* p = base + off; off += (bytes + 255) & ~(size_t)255; return p; };

  __hip_bfloat16* y0  = (__hip_bfloat16*)alloc((size_t)Tt*Mn*C2*2);
  __hip_bfloat16* tx1 = y0;
  __hip_bfloat16* tx2 = y0 + (size_t)Tt*Mn*Hh;
  // shared arena: pair (46.1 MB, dead after k_csr2) then urb (110.9 MB)
  char* arena = alloc((size_t)(NRND+1)*Tt*Mn*4);
  unsigned* pair = (unsigned*)arena;
  float*    urb  = (float*)arena;
  __hip_bfloat16* xbt = (__hip_bfloat16*)alloc((size_t)Tt*Mn*Hh*2);
  unsigned short* col16 = (unsigned short*)alloc((size_t)Tt*Ee*2);
  int*   rp   = (int*)alloc((size_t)Tt*(Mn+1)*4);
  int*   bcnt = (int*)alloc((size_t)Tt*NB*4);
  int*   bfill= (int*)alloc((size_t)Tt*NB*4);
  int*   rpb  = (int*)alloc((size_t)Tt*(NB+1)*4);
  float* dinv = (float*)alloc((size_t)Tt*Mn*4);
  float* lamc = (float*)alloc((size_t)2*Tt*4);
  float* WW   = (float*)alloc((size_t)3*Tt*Hh*Oo*4);
  float* c0   = (float*)alloc((size_t)Oo*4);
  __hip_bfloat16* Wbf = (__hip_bfloat16*)alloc((size_t)Gg*C2*2);
  int*   flagA = (int*)alloc((size_t)Tt*CHK*16*4);              // phase-A epoch flags, 64B apart
  unsigned long long* pbB = (unsigned long long*)alloc((size_t)Tt*CHK*16*8); // packed {epoch,partial}
  int*   prow = (int*)alloc((size_t)Tt*CHK*RC*4);               // degree-balanced row permutation
  (void)ws_size; (void)in_sizes; (void)n_in; (void)out_size;

  // CSR build: bucket histogram -> bucket scan -> partition -> per-bucket counting sort (emits rp+dinv)
  k_init<<<16, 256, 0, stream>>>(bcnt, bfill, flagA, pbB);
  k_bcnt<<<Tt*BPT, 256, 0, stream>>>(ei, bcnt);
  k_bscan<<<Tt, 256, 0, stream>>>(bcnt, rpb);
  k_part2<<<Tt*BPT, 256, 0, stream>>>(ei, rpb, bfill, pair);
  k_csr2<<<Tt*NB, 256, 0, stream>>>(rpb, pair, col16, rp, dinv);
  k_perm<<<Tt*CHK, 1024, 0, stream>>>(rp, prow);

  // GRU stack (MFMA; gi intermediate eliminated -- projection fused into gru1r)
  k_wcvt<<<(Gg*C2 + 255)/256, 256, 0, stream>>>(Wih1 + (size_t)Gg*C2, Wbf);
  k_gru0<<<SEGS, 256, 0, stream>>>(nf, Wih0, Whh0, bih0, bhh0, y0);
  k_gru1r<<<SEGS, 256, 0, stream>>>(y0, Wbf, Whh1 + (size_t)Gg*Hh,
                                    bih1 + Gg, bhh1 + Gg, lns, lnb, xbt);

  // power iteration: 75 rounds + 1 Rayleigh round; degree-balanced rows;
  // split into two launches (barrier state is global -> split is free)
  k_pitall<<<Tt*CHK, 1024, 0, stream>>>(rp, col16, urb, flagA, pbB, lamc, prow, 1, 38);
  k_pitall<<<Tt*CHK, 1024, 0, stream>>>(rp, col16, urb, flagA, pbB, lamc, prow, 39, NRND);

  // Chebyshev: tx1 = Lhat(x), tx2 = 2*Lhat(tx1) - x
  k_cheb<<<(Tt*Mn)/4, 256, 0, stream>>>(xbt, xbt, tx1, rp, col16, dinv, lamc, 1.f, 0.f);
  k_cheb<<<(Tt*Mn)/4, 256, 0, stream>>>(tx1, xbt, tx2, rp, col16, dinv, lamc, 2.f, -1.f);

  // folded cheb-GEMM + conv + sigmoid
  k_ww<<<(3*Tt*Hh*Oo + 255)/256, 256, 0, stream>>>(chebW, chebb, convW, convb, WW, c0);
  k_final<<<(Mn + 63)/64, 256, 0, stream>>>(xbt, tx1, tx2, WW, c0, outp);
}

// Round 9
// 2794.698 us; speedup vs baseline: 1.0182x; 1.0182x over previous
//
#include <hip/hip_runtime.h>
#include <hip/hip_bf16.h>

#define DEV __device__ __forceinline__

constexpr int Mn  = 30000;   // nodes (B=1)
constexpr int Tt  = 12;
constexpr int CIN = 16;
constexpr int Hh  = 64;
constexpr int Gg  = 192;     // 3H
constexpr int C2  = 128;     // 2H
constexpr int Ee  = 960000;  // edges per timestep (bidirectional)
constexpr int HC  = 128;
constexpr int Oo  = 12;
constexpr int KW  = 128;
constexpr int SEGS= 938;     // 32-row segments per t (938*32 >= 30000)
constexpr int NB  = 235;     // 128-row buckets per t (235*128 >= 30000)
constexpr int EPB = 8192;    // edges per block for bcnt/part2
constexpr int BPT = 118;     // ceil(Ee/EPB)
constexpr int CHK = 21;      // chunks per t for power iteration (252 blocks total)
constexpr int RC  = 1440;    // rows per chunk (16B-aligned; last chunk has 1200 real rows)
constexpr int UP  = CHK*RC;  // 30240 = permuted-space vector length per t (incl. holes)
constexpr int NRND= 76;      // 75 power rounds + 1 Rayleigh round
constexpr int NF4A= 21*256;  // phase-A float4 count (new-pos [0,1024) per chunk)
constexpr int NF4B= 21*104;  // phase-B float4 count (new-pos [1024,1440) per chunk, uniform)

DEV float bf2f(__hip_bfloat16 v){ return __bfloat162float(v); }
DEV __hip_bfloat16 f2bf(float v){ return __float2bfloat16(v); }
DEV float sigm(float x){ return __builtin_amdgcn_rcpf(1.f + __expf(-x)); }
DEV float tanh_f(float x){ return 1.f - 2.f*__builtin_amdgcn_rcpf(__expf(2.f*x) + 1.f); }

// agent-scope (device-coherent, sc1) accessors for cross-XCD flags/u-stores
DEV float aload_f(const float* p){ return __hip_atomic_load(p, __ATOMIC_RELAXED, __HIP_MEMORY_SCOPE_AGENT); }
DEV void  astore_f(float* p, float v){ __hip_atomic_store(p, v, __ATOMIC_RELAXED, __HIP_MEMORY_SCOPE_AGENT); }
DEV int   aload_i(const int* p){ return __hip_atomic_load(p, __ATOMIC_RELAXED, __HIP_MEMORY_SCOPE_AGENT); }
DEV void  astore_i(int* p, int v){ __hip_atomic_store(p, v, __ATOMIC_RELAXED, __HIP_MEMORY_SCOPE_AGENT); }
DEV unsigned long long aload_u64(const unsigned long long* p){ return __hip_atomic_load(p, __ATOMIC_RELAXED, __HIP_MEMORY_SCOPE_AGENT); }
DEV void astore_u64(unsigned long long* p, unsigned long long v){ __hip_atomic_store(p, v, __ATOMIC_RELAXED, __HIP_MEMORY_SCOPE_AGENT); }

typedef short bfrag8 __attribute__((ext_vector_type(8)));
typedef float ffrag4 __attribute__((ext_vector_type(4)));

// swizzled element offset into a [32 rows][64 cols] bf16 h-tile
DEV int off_h(int row, int col){
  return row*64 + ((((col >> 3) ^ (row & 7)) << 3) | (col & 7));
}

DEV short bfbits(float v){ __hip_bfloat16 b = f2bf(v); return *reinterpret_cast<short*>(&b); }

// ---------------------------------------------------------------- init (flags + CSR counters only)
__global__ void k_init(int* bcnt, int* bfill, int* flagA, unsigned long long* pbB){
  int i = blockIdx.x*256 + threadIdx.x;
  if (i < Tt*CHK*16){ flagA[i] = 0; pbB[i] = 0ull; }
  if (i < Tt*NB){ bcnt[i] = 0; bfill[i] = 0; }
}

// ---------------------------------------------------------------- stage 1: block-aggregated bucket histogram
__global__ __launch_bounds__(256) void k_bcnt(const int* __restrict__ ei, int* __restrict__ bcnt){
  __shared__ int h[NB];
  const int b = blockIdx.x;                 // 1416 = 8*177
  const int w = (b & 7)*177 + (b >> 3);
  const int t = w / BPT, ch = w - t*BPT;
  const int e0 = ch*EPB;
  const int tid = threadIdx.x;
  for (int i = tid; i < NB; i += 256) h[i] = 0;
  __syncthreads();
  #pragma unroll
  for (int i = 0; i < 32; ++i){
    int e = e0 + i*256 + tid;
    if (e < Ee){
      int r = ei[(size_t)(t*2)*Ee + e];
      atomicAdd(&h[r >> 7], 1);
    }
  }
  __syncthreads();
  for (int i = tid; i < NB; i += 256){
    int c = h[i];
    if (c > 0) atomicAdd(&bcnt[t*NB + i], c);
  }
}

// ---------------------------------------------------------------- stage 2: per-t exclusive scan of bucket counts
__global__ __launch_bounds__(256) void k_bscan(const int* __restrict__ bcnt, int* __restrict__ rpb){
  int t = blockIdx.x, tid = threadIdx.x;
  __shared__ int ps[256];
  int v = (tid < NB) ? bcnt[t*NB + tid] : 0;
  ps[tid] = v;
  __syncthreads();
  for (int o = 1; o < 256; o <<= 1){
    int x = (tid >= o) ? ps[tid-o] : 0;
    __syncthreads();
    ps[tid] += x;
    __syncthreads();
  }
  if (tid < NB) rpb[t*(NB+1) + tid] = ps[tid] - v;
  if (tid == 255) rpb[t*(NB+1) + NB] = ps[NB-1];
}

// ---------------------------------------------------------------- stage 3: partition edges into buckets (block-aggregated reservations)
__global__ __launch_bounds__(256) void k_part2(const int* __restrict__ ei, const int* __restrict__ rpb,
    int* __restrict__ bfill, unsigned* __restrict__ pair){
  __shared__ int hcnt[NB];
  __shared__ int hbase[NB];
  const int b = blockIdx.x;                 // 1416 = 8*177
  const int w = (b & 7)*177 + (b >> 3);
  const int t = w / BPT, ch = w - t*BPT;
  const int e0 = ch*EPB;
  const int tid = threadIdx.x;
  for (int i = tid; i < NB; i += 256) hcnt[i] = 0;
  __syncthreads();
  unsigned key[32];
  #pragma unroll
  for (int i = 0; i < 32; ++i){
    int e = e0 + i*256 + tid;
    unsigned k = 0xFFFFFFFFu;
    if (e < Ee){
      int r = ei[(size_t)(t*2)*Ee + e];
      int c = ei[(size_t)(t*2+1)*Ee + e];
      k = ((unsigned)r << 16) | (unsigned)c;
      atomicAdd(&hcnt[r >> 7], 1);
    }
    key[i] = k;
  }
  __syncthreads();
  for (int i = tid; i < NB; i += 256){
    int cnt = hcnt[i];
    int base = (cnt > 0) ? atomicAdd(&bfill[t*NB + i], cnt) : 0;
    hbase[i] = rpb[t*(NB+1) + i] + base;
  }
  __syncthreads();
  for (int i = tid; i < NB; i += 256) hcnt[i] = 0;
  __syncthreads();
  #pragma unroll
  for (int i = 0; i < 32; ++i){
    unsigned k = key[i];
    if (k != 0xFFFFFFFFu){
      int r = (int)(k >> 16);
      int bk = r >> 7;
      int pos = atomicAdd(&hcnt[bk], 1);
      pair[(size_t)t*Ee + hbase[bk] + pos] = ((unsigned)(r & 127) << 16) | (k & 0xFFFFu);
    }
  }
}

// ---------------------------------------------------------------- stage 4: per-bucket LDS counting sort -> col16, rp, dinv
__global__ __launch_bounds__(256) void k_csr2(const int* __restrict__ rpb, const unsigned* __restrict__ pair,
    unsigned short* __restrict__ col16, int* __restrict__ rp, float* __restrict__ dinv){
  __shared__ unsigned short cols_s[9216];
  __shared__ int lcnt[128], lfill[128];
  __shared__ int ps[256];
  const int blk = blockIdx.x;               // Tt*NB
  const int t = blk / NB, bk = blk - t*NB;
  const int r0 = bk << 7;
  const int nr = (r0 + 128 <= Mn) ? 128 : (Mn - r0);
  const int base = rpb[t*(NB+1) + bk];
  const int cnt  = rpb[t*(NB+1) + bk + 1] - base;
  const int tid = threadIdx.x;
  if (tid < 128) lcnt[tid] = 0;
  __syncthreads();
  for (int i = tid; i < cnt; i += 256){
    unsigned v = pair[(size_t)t*Ee + base + i];
    atomicAdd(&lcnt[v >> 16], 1);
  }
  __syncthreads();
  int v2 = (tid < 128) ? lcnt[tid] : 0;
  ps[tid] = v2;
  __syncthreads();
  for (int o = 1; o < 128; o <<= 1){
    int x = (tid >= o) ? ps[tid-o] : 0;
    __syncthreads();
    ps[tid] += x;
    __syncthreads();
  }
  if (tid < 128){
    int excl = ps[tid] - v2;
    lfill[tid] = excl;
    if (tid < nr){
      rp[t*(Mn+1) + r0 + tid] = base + excl;
      dinv[t*Mn + r0 + tid] = (v2 > 0) ? rsqrtf((float)v2) : 0.f;  // folded k_dinv
    }
  }
  if (bk == NB-1 && tid == 0) rp[t*(Mn+1) + Mn] = base + cnt;
  __syncthreads();
  for (int i = tid; i < cnt; i += 256){
    unsigned v = pair[(size_t)t*Ee + base + i];
    int pos = atomicAdd(&lfill[v >> 16], 1);
    cols_s[pos] = (unsigned short)(v & 0xFFFFu);
  }
  __syncthreads();
  for (int i = tid; i < cnt; i += 256)
    col16[(size_t)t*Ee + base + i] = cols_s[i];
}

// ---------------------------------------------------------------- degree-balanced row permutation per (t,chunk)
// Counting-sort of the chunk's rows by degree. prow: new-pos -> old row.
// imap: old row -> new-space index (ch*RC + pos). pitall runs entirely in
// new space (coalesced u stores); k_cheb keeps the original col16.
__global__ __launch_bounds__(1024) void k_perm(const int* __restrict__ rp,
    int* __restrict__ prow, int* __restrict__ imap){
  __shared__ int hist[256], hbase[256], ps[256];
  const int b = blockIdx.x;                 // Tt*CHK
  const int t = b / CHK, ch = b - t*CHK;
  const int r0 = ch*RC;
  const int r1 = (r0 + RC < Mn) ? r0 + RC : Mn;
  const int n = r1 - r0;
  const int tid = threadIdx.x;
  if (tid < 256) hist[tid] = 0;
  __syncthreads();
  const int* rpt = rp + t*(Mn+1);
  int d0 = -1, d1 = -1;
  if (tid < n){ int m = r0 + tid; d0 = min(rpt[m+1]-rpt[m], 255); atomicAdd(&hist[d0], 1); }
  if (1024 + tid < n){ int m = r0 + 1024 + tid; d1 = min(rpt[m+1]-rpt[m], 255); atomicAdd(&hist[d1], 1); }
  __syncthreads();
  if (tid < 256) ps[tid] = hist[tid];
  __syncthreads();
  for (int o = 1; o < 256; o <<= 1){
    int x = (tid >= o && tid < 256) ? ps[tid-o] : 0;
    __syncthreads();
    if (tid < 256) ps[tid] += x;
    __syncthreads();
  }
  if (tid < 256){ hbase[tid] = ps[tid] - hist[tid]; hist[tid] = 0; }
  __syncthreads();
  if (d0 >= 0){
    int pos = hbase[d0] + atomicAdd(&hist[d0], 1);
    prow[(size_t)b*RC + pos] = r0 + tid;
    imap[t*Mn + r0 + tid] = ch*RC + pos;
  }
  if (d1 >= 0){
    int pos = hbase[d1] + atomicAdd(&hist[d1], 1);
    prow[(size_t)b*RC + pos] = r0 + 1024 + tid;
    imap[t*Mn + r0 + 1024 + tid] = ch*RC + pos;
  }
}

// ---------------------------------------------------------------- remap columns into permuted space (one-time, 23MB pass)
__global__ __launch_bounds__(256) void k_remap(const unsigned short* __restrict__ col16,
    const int* __restrict__ imap, unsigned short* __restrict__ colp){
  const size_t total4 = (size_t)Tt*Ee/4;
  for (size_t i = (size_t)blockIdx.x*256 + threadIdx.x; i < total4; i += (size_t)gridDim.x*256){
    int t = (int)((i*4) / Ee);
    const int* mp = imap + (size_t)t*Mn;
    ushort4 c = ((const ushort4*)col16)[i];
    ushort4 o;
    o.x = (unsigned short)mp[c.x]; o.y = (unsigned short)mp[c.y];
    o.z = (unsigned short)mp[c.z]; o.w = (unsigned short)mp[c.w];
    ((ushort4*)colp)[i] = o;
  }
}

// ---------------------------------------------------------------- GRU layer 0 (both dirs) via MFMA, writes y0 (T,M,128) bf16
__global__ __launch_bounds__(256) void k_gru0(
    const float* __restrict__ nf, const float* __restrict__ Wih, const float* __restrict__ Whh,
    const float* __restrict__ bih, const float* __restrict__ bhh, __hip_bfloat16* __restrict__ y0)
{
  __shared__ __hip_bfloat16 xp[Tt*32*32];   // [t][row][k]: cols 0-15 x_hi, 16-31 x_lo (24.6 KB)
  __shared__ __hip_bfloat16 h_hi[32*64];    // swizzled (4 KB)
  __shared__ __hip_bfloat16 h_lo[32*64];    // swizzled (4 KB)
  const int tid = threadIdx.x;
  const int m0  = blockIdx.x*32;
  const int lane = tid & 63, wv = tid >> 6;
  const int lr = lane & 15, lq = lane >> 4;
  for (int idx = tid; idx < Tt*32*CIN; idx += 256){
    int t = idx >> 9; int row = (idx >> 4) & 31; int k = idx & 15;
    int m = m0 + row;
    float v = (m < Mn) ? nf[((size_t)t*Mn + m)*CIN + k] : 0.f;
    __hip_bfloat16 hi = f2bf(v);
    xp[(t*32 + row)*32 + k]      = hi;
    xp[(t*32 + row)*32 + 16 + k] = f2bf(v - bf2f(hi));
  }
  for (int d = 0; d < 2; ++d){
    bfrag8 Bh[3][2], Bx[3];
    float b_r, b_z, b_in, b_hn;
    {
      const float* Wh = Whh + (size_t)d*Gg*Hh;
      const float* Wx = Wih + (size_t)d*Gg*CIN;
      #pragma unroll
      for (int c = 0; c < 3; ++c){
        int g = (wv + 4*c)*16 + lr;
        #pragma unroll
        for (int ks = 0; ks < 2; ++ks){
          bfrag8 f;
          #pragma unroll
          for (int r = 0; r < 8; ++r) f[r] = bfbits(Wh[(size_t)g*Hh + ks*32 + lq*8 + r]);
          Bh[c][ks] = f;
        }
        bfrag8 fx;
        #pragma unroll
        for (int r = 0; r < 8; ++r) fx[r] = bfbits(Wx[(size_t)g*CIN + ((lq*8 + r) & 15)]);
        Bx[c] = fx;
      }
      int j = wv*16 + lr;
      b_r  = bih[d*Gg + j]        + bhh[d*Gg + j];
      b_z  = bih[d*Gg + Hh + j]   + bhh[d*Gg + Hh + j];
      b_in = bih[d*Gg + 2*Hh + j];
      b_hn = bhh[d*Gg + 2*Hh + j];
    }
    float hreg[8];
    #pragma unroll
    for (int q = 0; q < 8; ++q) hreg[q] = 0.f;
    for (int i = tid; i < 32*64; i += 256){ h_hi[i] = f2bf(0.f); h_lo[i] = f2bf(0.f); }
    __syncthreads();
    for (int step = 0; step < Tt; ++step){
      int t = d ? (Tt-1-step) : step;
      bfrag8 xa[2], hhf[2][2], hlf[2][2];
      #pragma unroll
      for (int rt = 0; rt < 2; ++rt){
        int row = rt*16 + lr;
        xa[rt] = *(const bfrag8*)&xp[(t*32 + row)*32 + lq*8];
        #pragma unroll
        for (int ks = 0; ks < 2; ++ks){
          int e = off_h(row, ks*32 + lq*8);
          hhf[rt][ks] = *(const bfrag8*)&h_hi[e];
          hlf[rt][ks] = *(const bfrag8*)&h_lo[e];
        }
      }
      ffrag4 Cr[2], Cz[2], Cai[2], Cah[2];
      #pragma unroll
      for (int rt = 0; rt < 2; ++rt){
        ffrag4 z4 = (ffrag4){0.f,0.f,0.f,0.f};
        Cr[rt]  = __builtin_amdgcn_mfma_f32_16x16x32_bf16(xa[rt], Bx[0], z4, 0,0,0);
        Cz[rt]  = __builtin_amdgcn_mfma_f32_16x16x32_bf16(xa[rt], Bx[1], z4, 0,0,0);
        Cai[rt] = __builtin_amdgcn_mfma_f32_16x16x32_bf16(xa[rt], Bx[2], z4, 0,0,0);
        Cah[rt] = z4;
        #pragma unroll
        for (int ks = 0; ks < 2; ++ks){
          Cr[rt]  = __builtin_amdgcn_mfma_f32_16x16x32_bf16(hhf[rt][ks], Bh[0][ks], Cr[rt], 0,0,0);
          Cr[rt]  = __builtin_amdgcn_mfma_f32_16x16x32_bf16(hlf[rt][ks], Bh[0][ks], Cr[rt], 0,0,0);
          Cz[rt]  = __builtin_amdgcn_mfma_f32_16x16x32_bf16(hhf[rt][ks], Bh[1][ks], Cz[rt], 0,0,0);
          Cz[rt]  = __builtin_amdgcn_mfma_f32_16x16x32_bf16(hlf[rt][ks], Bh[1][ks], Cz[rt], 0,0,0);
          Cah[rt] = __builtin_amdgcn_mfma_f32_16x16x32_bf16(hhf[rt][ks], Bh[2][ks], Cah[rt], 0,0,0);
          Cah[rt] = __builtin_amdgcn_mfma_f32_16x16x32_bf16(hlf[rt][ks], Bh[2][ks], Cah[rt], 0,0,0);
        }
      }
      __syncthreads();
      #pragma unroll
      for (int rt = 0; rt < 2; ++rt){
        #pragma unroll
        for (int q = 0; q < 4; ++q){
          float r = sigm(Cr[rt][q] + b_r);
          float z = sigm(Cz[rt][q] + b_z);
          float n = tanh_f((Cai[rt][q] + b_in) + r*(Cah[rt][q] + b_hn));
          float h = (1.f - z)*n + z*hreg[rt*4+q];
          hreg[rt*4+q] = h;
          __hip_bfloat16 hi = f2bf(h);
          int e = off_h(rt*16 + lq*4 + q, wv*16 + lr);
          h_hi[e] = hi;
          h_lo[e] = f2bf(h - bf2f(hi));
        }
      }
      __syncthreads();
      {
        int row = tid >> 3, cg = tid & 7;
        int m = m0 + row;
        if (m < Mn){
          float4 v = *(const float4*)&h_hi[off_h(row, cg*8)];
          *(float4*)&y0[((size_t)t*Mn + m)*C2 + d*Hh + cg*8] = v;
        }
      }
    }
    __syncthreads();
  }
}

// ---------------------------------------------------------------- convert layer-1 reverse Wih to bf16
__global__ void k_wcvt(const float* __restrict__ W, __hip_bfloat16* __restrict__ Wbf){
  int i = blockIdx.x*256 + threadIdx.x;
  if (i < Gg*C2) Wbf[i] = f2bf(W[i]);
}

// ---------------------------------------------------------------- GRU layer 1 (reverse) via MFMA with FUSED input projection
__global__ __launch_bounds__(256) void k_gru1r(const __hip_bfloat16* __restrict__ y0,
    const __hip_bfloat16* __restrict__ Wbf, const float* __restrict__ Whh,
    const float* __restrict__ bih, const float* __restrict__ bhh,
    const float* __restrict__ lns, const float* __restrict__ lnb,
    __hip_bfloat16* __restrict__ xbt)
{
  __shared__ __hip_bfloat16 h_hi[32*64];    // swizzled (4 KB)
  __shared__ __hip_bfloat16 h_lo[32*64];
  __shared__ float h_f32[32*72];            // exact f32 h for LayerNorm (9.2 KB)
  __shared__ float sc[Hh], bs[Hh];
  const int tid = threadIdx.x;
  const int seg = blockIdx.x;
  const int m0  = seg*32;
  const int lane = tid & 63, wv = tid >> 6;
  const int lr = lane & 15, lq = lane >> 4;
  bfrag8 Bh[3][2];
  #pragma unroll
  for (int c = 0; c < 3; ++c){
    int g = (wv + 4*c)*16 + lr;
    #pragma unroll
    for (int ks = 0; ks < 2; ++ks){
      bfrag8 f;
      #pragma unroll
      for (int r = 0; r < 8; ++r) f[r] = bfbits(Whh[(size_t)g*Hh + ks*32 + lq*8 + r]);
      Bh[c][ks] = f;
    }
  }
  bfrag8 Bp[3][4];
  #pragma unroll
  for (int c = 0; c < 3; ++c){
    int g = (wv + 4*c)*16 + lr;
    #pragma unroll
    for (int ks = 0; ks < 4; ++ks)
      Bp[c][ks] = *(const bfrag8*)(Wbf + (size_t)g*C2 + ks*32 + lq*8);
  }
  float b_r, b_z, b_in, b_hn;
  {
    int j = wv*16 + lr;
    b_r  = bih[j]      + bhh[j];
    b_z  = bih[Hh+j]   + bhh[Hh+j];
    b_in = bih[2*Hh+j];
    b_hn = bhh[2*Hh+j];
  }
  if (tid < Hh){ sc[tid] = lns[tid]; bs[tid] = lnb[tid]; }
  float hreg[8];
  #pragma unroll
  for (int q = 0; q < 8; ++q) hreg[q] = 0.f;
  for (int i = tid; i < 32*64; i += 256){ h_hi[i] = f2bf(0.f); h_lo[i] = f2bf(0.f); }
  __syncthreads();
  for (int step = 0; step < Tt; ++step){
    int t = Tt-1-step;
    const __hip_bfloat16* yb = y0 + (size_t)t*Mn*C2;
    ffrag4 Cr[2], Cz[2], Cai[2], Cah[2];
    #pragma unroll
    for (int rt = 0; rt < 2; ++rt){
      ffrag4 z4 = (ffrag4){0.f,0.f,0.f,0.f};
      Cr[rt] = z4; Cz[rt] = z4; Cai[rt] = z4; Cah[rt] = z4;
    }
    #pragma unroll
    for (int ks = 0; ks < 4; ++ks){
      const int ko = ks*32 + lq*8;
      bfrag8 a0 = *(const bfrag8*)(yb + (size_t)(m0 + lr     )*C2 + ko);
      bfrag8 a1 = *(const bfrag8*)(yb + (size_t)(m0 + 16 + lr)*C2 + ko);
      Cr[0]  = __builtin_amdgcn_mfma_f32_16x16x32_bf16(a0, Bp[0][ks], Cr[0], 0,0,0);
      Cr[1]  = __builtin_amdgcn_mfma_f32_16x16x32_bf16(a1, Bp[0][ks], Cr[1], 0,0,0);
      Cz[0]  = __builtin_amdgcn_mfma_f32_16x16x32_bf16(a0, Bp[1][ks], Cz[0], 0,0,0);
      Cz[1]  = __builtin_amdgcn_mfma_f32_16x16x32_bf16(a1, Bp[1][ks], Cz[1], 0,0,0);
      Cai[0] = __builtin_amdgcn_mfma_f32_16x16x32_bf16(a0, Bp[2][ks], Cai[0], 0,0,0);
      Cai[1] = __builtin_amdgcn_mfma_f32_16x16x32_bf16(a1, Bp[2][ks], Cai[1], 0,0,0);
    }
    bfrag8 hhf[2][2], hlf[2][2];
    #pragma unroll
    for (int rt = 0; rt < 2; ++rt){
      int row = rt*16 + lr;
      #pragma unroll
      for (int ks = 0; ks < 2; ++ks){
        int e = off_h(row, ks*32 + lq*8);
        hhf[rt][ks] = *(const bfrag8*)&h_hi[e];
        hlf[rt][ks] = *(const bfrag8*)&h_lo[e];
      }
    }
    #pragma unroll
    for (int rt = 0; rt < 2; ++rt){
      #pragma unroll
      for (int ks = 0; ks < 2; ++ks){
        Cr[rt]  = __builtin_amdgcn_mfma_f32_16x16x32_bf16(hhf[rt][ks], Bh[0][ks], Cr[rt], 0,0,0);
        Cr[rt]  = __builtin_amdgcn_mfma_f32_16x16x32_bf16(hlf[rt][ks], Bh[0][ks], Cr[rt], 0,0,0);
        Cz[rt]  = __builtin_amdgcn_mfma_f32_16x16x32_bf16(hhf[rt][ks], Bh[1][ks], Cz[rt], 0,0,0);
        Cz[rt]  = __builtin_amdgcn_mfma_f32_16x16x32_bf16(hlf[rt][ks], Bh[1][ks], Cz[rt], 0,0,0);
        Cah[rt] = __builtin_amdgcn_mfma_f32_16x16x32_bf16(hhf[rt][ks], Bh[2][ks], Cah[rt], 0,0,0);
        Cah[rt] = __builtin_amdgcn_mfma_f32_16x16x32_bf16(hlf[rt][ks], Bh[2][ks], Cah[rt], 0,0,0);
      }
    }
    __syncthreads();
    #pragma unroll
    for (int rt = 0; rt < 2; ++rt){
      #pragma unroll
      for (int q = 0; q < 4; ++q){
        float r = sigm(Cr[rt][q] + b_r);
        float z = sigm(Cz[rt][q] + b_z);
        float n = tanh_f((Cai[rt][q] + b_in) + r*(Cah[rt][q] + b_hn));
        float h = (1.f - z)*n + z*hreg[rt*4+q];
        hreg[rt*4+q] = h;
        __hip_bfloat16 hi = f2bf(h);
        int row = rt*16 + lq*4 + q;
        int e = off_h(row, wv*16 + lr);
        h_hi[e] = hi;
        h_lo[e] = f2bf(h - bf2f(hi));
        h_f32[row*72 + wv*16 + lr] = h;
      }
    }
    __syncthreads();
    {
      int row = tid >> 3, l = tid & 7;
      float4 v0 = *(const float4*)&h_f32[row*72 + l*8];
      float4 v1 = *(const float4*)&h_f32[row*72 + l*8 + 4];
      float vals[8] = {v0.x, v0.y, v0.z, v0.w, v1.x, v1.y, v1.z, v1.w};
      float s1 = 0.f, s2 = 0.f;
      #pragma unroll
      for (int q = 0; q < 8; ++q){ s1 += vals[q]; s2 += vals[q]*vals[q]; }
      #pragma unroll
      for (int off = 1; off <= 4; off <<= 1){ s1 += __shfl_xor(s1, off); s2 += __shfl_xor(s2, off); }
      float mu  = s1 * (1.f/64.f);
      float var = s2 * (1.f/64.f) - mu*mu;
      float rs  = rsqrtf(var + 1e-5f);
      int m = m0 + row;
      if (m < Mn){
        __hip_bfloat16 ob[8];
        #pragma unroll
        for (int q = 0; q < 8; ++q){ int j = l*8 + q; ob[q] = f2bf((vals[q]-mu)*rs*sc[j] + bs[j]); }
        *(float4*)&xbt[((size_t)t*Mn + m)*Hh + l*8] = *(float4*)ob;
      }
    }
    __syncthreads();
  }
}

// ---------------------------------------------------------------- fused power iteration in PERMUTED space
// Degree-balanced thread->row mapping (prow) with COALESCED stores: u lives
// permuted (new index = ch*RC + degree-sorted pos; holes in last chunk are
// never referenced). Gather uses colp (columns remapped to new space). Sync
// structure identical to the validated R5 design. Single launch again.
__global__ __launch_bounds__(1024) void k_pitall(const int* __restrict__ rp,
    const unsigned short* __restrict__ colp, float* __restrict__ urb,
    int* __restrict__ flagA, unsigned long long* __restrict__ pbB,
    float* __restrict__ lamc, const int* __restrict__ prow)
{
  __shared__ alignas(16) float u_s[UP];     // 120960 B
  __shared__ float redw[16];
  __shared__ float s_nrm;
  __shared__ int s_goA, s_goB;
  const int b = blockIdx.x;                 // Tt*CHK = 252
  const int t = b / CHK, ch = b - t*CHK;
  const int r0 = ch*RC;
  const int n = (r0 + RC < Mn) ? RC : (Mn - r0);   // real rows in chunk (1440 or 1200)
  const int tid = threadIdx.x;
  const int lane = tid & 63;
  const int wv   = tid >> 6;                // wave id 0..15
  const unsigned short* cp = colp + (size_t)t*Ee;
  const int fS = t*CHK*16;                  // flagA slots: u32, 64B apart
  const int pS = t*CHK*16;                  // pbB slots: u64, per block 2 parity x 64B
  // degree-balanced rows; phase A = new pos tid (<1024, always real),
  // phase B = new pos 1024+tid (guarded by n)
  const int posA = tid, posB = 1024 + tid;
  const int rowA = prow[(size_t)b*RC + posA];
  const int rowB = (posB < n) ? prow[(size_t)b*RC + posB] : -1;
  const int newA = ch*RC + posA;
  const int newB = ch*RC + posB;
  int rb0 = 0, re0 = 0, rb1 = 0, re1 = 0;
  {
    const int* rpt = rp + t*(Mn+1);
    rb0 = rpt[rowA]; re0 = rpt[rowA+1];
    if (rowB >= 0){ rb1 = rpt[rowB]; re1 = rpt[rowB+1]; }
  }
  if (tid == 0){ s_nrm = 1.0f; s_goA = 0; s_goB = 0; }
  __syncthreads();
  for (int r = 1; r <= NRND; ++r){
    const int fin = (r == NRND);
    if (r == 1){
      for (int i = tid; i < UP; i += 1024) u_s[i] = 0.005773502691896258f;
    } else {
      const int rr = r - 1;
      const float4* u4 = (const float4*)(urb + (size_t)rr*(Tt*UP) + (size_t)t*UP);
      float4* s4 = (float4*)u_s;
      if (wv == 0){
        const bool mine = lane < CHK;
        for (;;){ int v = mine ? aload_i(&flagA[fS + lane*16]) : 0x7FFFFFFF;
                  if (__all(v >= rr)) break; __builtin_amdgcn_s_sleep(4); }
        if (lane == 0) __hip_atomic_store(&s_goA, rr, __ATOMIC_RELAXED, __HIP_MEMORY_SCOPE_WORKGROUP);
      } else {
        while (__hip_atomic_load(&s_goA, __ATOMIC_RELAXED, __HIP_MEMORY_SCOPE_WORKGROUP) < rr)
          __builtin_amdgcn_s_sleep(2);
      }
      asm volatile("" ::: "memory");
      for (int i = tid; i < NF4A; i += 1024){
        int idx = (i >> 8)*360 + (i & 255);  // first 256 f4 (pos 0..1023) per chunk
        s4[idx] = u4[idx];
      }
      unsigned long long pv = 0;
      if (wv == 0){
        const bool mine = lane < CHK;
        for (;;){ pv = mine ? aload_u64(&pbB[(size_t)(pS + lane*16) + (rr & 1)*8])
                            : ((unsigned long long)rr << 32);
                  if (__all((int)(pv >> 32) == rr)) break; __builtin_amdgcn_s_sleep(4); }
        if (lane == 0) __hip_atomic_store(&s_goB, rr, __ATOMIC_RELAXED, __HIP_MEMORY_SCOPE_WORKGROUP);
      } else {
        while (__hip_atomic_load(&s_goB, __ATOMIC_RELAXED, __HIP_MEMORY_SCOPE_WORKGROUP) < rr)
          __builtin_amdgcn_s_sleep(2);
      }
      asm volatile("" ::: "memory");
      for (int i = tid; i < NF4B; i += 1024){
        int ck = i/104, off = i - ck*104;    // f4 256..359 (pos 1024..1439) per chunk
        int idx = ck*360 + 256 + off;
        s4[idx] = u4[idx];
      }
      if (wv == 0){
        float p = (lane < CHK) ? __uint_as_float((unsigned)pv) : 0.f;
        #pragma unroll
        for (int o2 = 1; o2 < 32; o2 <<= 1) p += __shfl_xor(p, o2);
        if (tid == 0) s_nrm = p;
      }
    }
    __syncthreads();
    const float inv_s = fin ? 1.f : 1.f/(sqrtf(s_nrm) + 1e-12f);
    float* u_ot = urb + (size_t)r*(Tt*UP) + (size_t)t*UP;
    float local = 0.f;
    // ---- phase A (always active; store coalesced at newA)
    {
      float s = 0.f;
      int i = rb0;
      for (; i < re0 && (i & 3); ++i) s += u_s[cp[i]];
      for (; i + 4 <= re0; i += 4){
        ushort4 c4 = *(const ushort4*)(cp + i);
        s += (u_s[c4.x] + u_s[c4.y]) + (u_s[c4.z] + u_s[c4.w]);
      }
      for (; i < re0; ++i) s += u_s[cp[i]];
      float uv = u_s[newA];
      float wv2 = (float)(re0 - rb0)*uv - s;
      if (!fin){ float o = inv_s*wv2; astore_f(&u_ot[newA], o); local += o*o; }
      else local += uv*wv2;
    }
    asm volatile("s_waitcnt vmcnt(0)" ::: "memory");
    __syncthreads();
    if (tid == 0) astore_i(&flagA[fS + ch*16], r);
    // ---- phase B
    if (rowB >= 0){
      float s = 0.f;
      int i = rb1;
      for (; i < re1 && (i & 3); ++i) s += u_s[cp[i]];
      for (; i + 4 <= re1; i += 4){
        ushort4 c4 = *(const ushort4*)(cp + i);
        s += (u_s[c4.x] + u_s[c4.y]) + (u_s[c4.z] + u_s[c4.w]);
      }
      for (; i < re1; ++i) s += u_s[cp[i]];
      float uv = u_s[newB];
      float wv2 = (float)(re1 - rb1)*uv - s;
      if (!fin){ float o = inv_s*wv2; astore_f(&u_ot[newB], o); local += o*o; }
      else local += uv*wv2;
    }
    #pragma unroll
    for (int o2 = 1; o2 < 64; o2 <<= 1) local += __shfl_xor(local, o2);
    if ((tid & 63) == 0) redw[tid >> 6] = local;
    asm volatile("s_waitcnt vmcnt(0)" ::: "memory");
    __syncthreads();
    if (tid < 64){
      float tot = (tid < 16) ? redw[tid] : 0.f;
      #pragma unroll
      for (int o2 = 1; o2 < 16; o2 <<= 1) tot += __shfl_xor(tot, o2);
      if (tid == 0){
        unsigned long long out = ((unsigned long long)r << 32)
                               | (unsigned long long)__float_as_uint(tot);
        astore_u64(&pbB[(size_t)(pS + ch*16) + (r & 1)*8], out);
      }
    }
  }
  // folded lamfin: ch==0 waits for the final packed partials
  if (ch == 0 && tid < 64){
    const bool mine = lane < CHK;
    unsigned long long pv = 0;
    for (;;){ pv = mine ? aload_u64(&pbB[(size_t)(pS + lane*16) + (NRND & 1)*8])
                        : ((unsigned long long)NRND << 32);
              if (__all((int)(pv >> 32) == NRND)) break; __builtin_amdgcn_s_sleep(4); }
    float p = mine ? __uint_as_float((unsigned)pv) : 0.f;
    #pragma unroll
    for (int o2 = 1; o2 < 32; o2 <<= 1) p += __shfl_xor(p, o2);
    if (tid == 0){
      float nn = sqrtf(s_nrm) + 1e-12f;
      float lam = p / (nn*nn);
      lamc[2*t+0] = -2.f/lam;
      lamc[2*t+1] =  2.f/lam - 1.f;
    }
  }
}

// ---------------------------------------------------------------- Chebyshev SpMM (wave per row, lane = channel, XCD-swizzled)
__global__ __launch_bounds__(256) void k_cheb(const __hip_bfloat16* __restrict__ xin,
    const __hip_bfloat16* __restrict__ xb0, __hip_bfloat16* __restrict__ outp,
    const int* __restrict__ rp, const unsigned short* __restrict__ col,
    const float* __restrict__ dinv, const float* __restrict__ lamc, float s1, float s2)
{
  const int blk = blockIdx.x;               // 90000 = 8*11250
  const int w = (blk & 7)*11250 + (blk >> 3);
  const int gw = w*4 + (threadIdx.x >> 6);
  const int lane = threadIdx.x & 63;
  int t = gw / Mn, m = gw - t*Mn;
  float coef = lamc[2*t], diag = lamc[2*t+1];
  const __hip_bfloat16* xt = xin + (size_t)t*Mn*Hh;
  const float* dv = dinv + t*Mn;
  float acc = diag * bf2f(xt[(size_t)m*Hh + lane]);
  float cdm = coef * dv[m];
  int bgn = rp[t*(Mn+1)+m], end = rp[t*(Mn+1)+m+1];
  const unsigned short* cp = col + (size_t)t*Ee;
  int i = bgn;
  for (; i < end && (i & 3); ++i){ int c = cp[i]; acc += (cdm*dv[c])*bf2f(xt[(size_t)c*Hh + lane]); }
  for (; i + 4 <= end; i += 4){
    ushort4 c4 = *(const ushort4*)(cp + i);
    float w0 = cdm*dv[c4.x], w1 = cdm*dv[c4.y], w2 = cdm*dv[c4.z], w3 = cdm*dv[c4.w];
    acc += w0*bf2f(xt[(size_t)c4.x*Hh + lane]);
    acc += w1*bf2f(xt[(size_t)c4.y*Hh + lane]);
    acc += w2*bf2f(xt[(size_t)c4.z*Hh + lane]);
    acc += w3*bf2f(xt[(size_t)c4.w*Hh + lane]);
  }
  for (; i < end; ++i){ int c = cp[i]; acc += (cdm*dv[c])*bf2f(xt[(size_t)c*Hh + lane]); }
  float o = s1*acc;
  if (s2 != 0.f) o += s2*bf2f(xb0[(size_t)gw*Hh + lane]);
  outp[(size_t)gw*Hh + lane] = f2bf(o);
}

// ---------------------------------------------------------------- fold cheb_W into conv_W
__global__ void k_ww(const float* __restrict__ chebW, const float* __restrict__ chebb,
    const float* __restrict__ convW, const float* __restrict__ convb, float* __restrict__ WW, float* __restrict__ c0)
{
  int idx = blockIdx.x*256 + threadIdx.x;
  if (idx < 3*Tt*Hh*Oo){
    int oc = idx % Oo; int j = (idx/Oo) % Hh; int t = (idx/(Oo*Hh)) % Tt; int i = idx/(Oo*Hh*Tt);
    const float* cw = chebW + ((size_t)i*Hh + j)*HC + (HC-KW);
    const float* vw = convW + ((size_t)oc*Tt + t)*KW;
    float s = 0.f;
    for (int k = 0; k < KW; ++k) s += cw[k]*vw[k];
    WW[idx] = s;
  }
  if (blockIdx.x == 0 && threadIdx.x < Oo){
    int oc = threadIdx.x;
    float s = convb[oc];
    for (int t = 0; t < Tt; ++t){
      const float* vw = convW + ((size_t)oc*Tt + t)*KW;
      for (int k = 0; k < KW; ++k) s += chebb[(HC-KW)+k]*vw[k];
    }
    c0[oc] = s;
  }
}

// ---------------------------------------------------------------- fused cheb-GEMM + temporal conv + sigmoid
__global__ __launch_bounds__(256) void k_final(const __hip_bfloat16* __restrict__ tx0,
    const __hip_bfloat16* __restrict__ tx1, const __hip_bfloat16* __restrict__ tx2,
    const float* __restrict__ WW, const float* __restrict__ c0, float* __restrict__ outp)
{
  __shared__ float xs[64][65];
  __shared__ float ww[64][12];
  const int tid = threadIdx.x;
  const int n0 = blockIdx.x*64;
  const int n = tid & 63, ob = (tid >> 6)*3;
  float acc[3] = {0.f, 0.f, 0.f};
  for (int it = 0; it < 3*Tt; ++it){
    int ii = it / Tt, t = it % Tt;
    const __hip_bfloat16* tx = (ii == 0) ? tx0 : (ii == 1) ? tx1 : tx2;
    __syncthreads();
    for (int idx = tid; idx < 64*64; idx += 256){
      int mm = idx >> 6, j = idx & 63;
      int m = n0 + mm;
      xs[mm][j] = (m < Mn) ? bf2f(tx[((size_t)t*Mn + m)*Hh + j]) : 0.f;
    }
    for (int idx = tid; idx < 64*Oo; idx += 256)
      ((float*)ww)[idx] = WW[((size_t)(ii*Tt + t)*Hh)*Oo + idx];
    __syncthreads();
    #pragma unroll 8
    for (int j = 0; j < 64; ++j){
      float x = xs[n][j];
      acc[0] += x*ww[j][ob+0];
      acc[1] += x*ww[j][ob+1];
      acc[2] += x*ww[j][ob+2];
    }
  }
  int m = n0 + n;
  if (m < Mn){
    #pragma unroll
    for (int q = 0; q < 3; ++q) outp[(size_t)m*Oo + ob + q] = sigm(acc[q] + c0[ob+q]);
  }
}

// ================================================================ host
extern "C" void kernel_launch(void* const* d_in, const int* in_sizes, int n_in,
                              void* d_out, int out_size, void* d_ws, size_t ws_size,
                              hipStream_t stream)
{
  const float* nf    = (const float*)d_in[0];
  const int*   ei    = (const int*)d_in[1];
  const float* Wih0  = (const float*)d_in[2];
  const float* Whh0  = (const float*)d_in[3];
  const float* bih0  = (const float*)d_in[4];
  const float* bhh0  = (const float*)d_in[5];
  const float* Wih1  = (const float*)d_in[6];
  const float* Whh1  = (const float*)d_in[7];
  const float* bih1  = (const float*)d_in[8];
  const float* bhh1  = (const float*)d_in[9];
  const float* lns   = (const float*)d_in[10];
  const float* lnb   = (const float*)d_in[11];
  const float* chebW = (const float*)d_in[12];
  const float* chebb = (const float*)d_in[13];
  const float* convW = (const float*)d_in[14];
  const float* convb = (const float*)d_in[15];
  float* outp = (float*)d_out;

  char* base = (char*)d_ws;
  size_t off = 0;
  auto alloc = [&](size_t bytes)->char*{ char* p = base + off; off += (bytes + 255) & ~(size_t)255; return p; };

  __hip_bfloat16* y0  = (__hip_bfloat16*)alloc((size_t)Tt*Mn*C2*2);
  __hip_bfloat16* tx1 = y0;
  __hip_bfloat16* tx2 = y0 + (size_t)Tt*Mn*Hh;
  // shared arena: pair (46.1 MB, dead after k_csr2) then urb ((77*12*30240*4)=111.8 MB)
  char* arena = alloc((size_t)(NRND+1)*Tt*UP*4);
  unsigned* pair = (unsigned*)arena;
  float*    urb  = (float*)arena;
  __hip_bfloat16* xbt = (__hip_bfloat16*)alloc((size_t)Tt*Mn*Hh*2);
  unsigned short* col16 = (unsigned short*)alloc((size_t)Tt*Ee*2);
  unsigned short* colp  = (unsigned short*)alloc((size_t)Tt*Ee*2);
  int*   rp   = (int*)alloc((size_t)Tt*(Mn+1)*4);
  int*   bcnt = (int*)alloc((size_t)Tt*NB*4);
  int*   bfill= (int*)alloc((size_t)Tt*NB*4);
  int*   rpb  = (int*)alloc((size_t)Tt*(NB+1)*4);
  float* dinv = (float*)alloc((size_t)Tt*Mn*4);
  float* lamc = (float*)alloc((size_t)2*Tt*4);
  float* WW   = (float*)alloc((size_t)3*Tt*Hh*Oo*4);
  float* c0   = (float*)alloc((size_t)Oo*4);
  __hip_bfloat16* Wbf = (__hip_bfloat16*)alloc((size_t)Gg*C2*2);
  int*   flagA = (int*)alloc((size_t)Tt*CHK*16*4);              // phase-A epoch flags, 64B apart
  unsigned long long* pbB = (unsigned long long*)alloc((size_t)Tt*CHK*16*8); // packed {epoch,partial}
  int*   prow = (int*)alloc((size_t)Tt*CHK*RC*4);               // new-pos -> old row
  int*   imap = (int*)alloc((size_t)Tt*Mn*4);                   // old row -> new index
  (void)ws_size; (void)in_sizes; (void)n_in; (void)out_size;

  // CSR build: bucket histogram -> bucket scan -> partition -> per-bucket counting sort (emits rp+dinv)
  k_init<<<16, 256, 0, stream>>>(bcnt, bfill, flagA, pbB);
  k_bcnt<<<Tt*BPT, 256, 0, stream>>>(ei, bcnt);
  k_bscan<<<Tt, 256, 0, stream>>>(bcnt, rpb);
  k_part2<<<Tt*BPT, 256, 0, stream>>>(ei, rpb, bfill, pair);
  k_csr2<<<Tt*NB, 256, 0, stream>>>(rpb, pair, col16, rp, dinv);
  k_perm<<<Tt*CHK, 1024, 0, stream>>>(rp, prow, imap);
  k_remap<<<2048, 256, 0, stream>>>(col16, imap, colp);

  // GRU stack (MFMA; gi intermediate eliminated -- projection fused into gru1r)
  k_wcvt<<<(Gg*C2 + 255)/256, 256, 0, stream>>>(Wih1 + (size_t)Gg*C2, Wbf);
  k_gru0<<<SEGS, 256, 0, stream>>>(nf, Wih0, Whh0, bih0, bhh0, y0);
  k_gru1r<<<SEGS, 256, 0, stream>>>(y0, Wbf, Whh1 + (size_t)Gg*Hh,
                                    bih1 + Gg, bhh1 + Gg, lns, lnb, xbt);

  // power iteration: 75 rounds + 1 Rayleigh, permuted space (balanced waves,
  // coalesced stores), single launch
  k_pitall<<<Tt*CHK, 1024, 0, stream>>>(rp, colp, urb, flagA, pbB, lamc, prow);

  // Chebyshev: tx1 = Lhat(x), tx2 = 2*Lhat(tx1) - x  (original-space col16)
  k_cheb<<<(Tt*Mn)/4, 256, 0, stream>>>(xbt, xbt, tx1, rp, col16, dinv, lamc, 1.f, 0.f);
  k_cheb<<<(Tt*Mn)/4, 256, 0, stream>>>(tx1, xbt, tx2, rp, col16, dinv, lamc, 2.f, -1.f);

  // folded cheb-GEMM + conv + sigmoid
  k_ww<<<(3*Tt*Hh*Oo + 255)/256, 256, 0, stream>>>(chebW, chebb, convW, convb, WW, c0);
  k_final<<<(Mn + 63)/64, 256, 0, stream>>>(xbt, tx1, tx2, WW, c0, outp);
}

// Round 10
// 2352.982 us; speedup vs baseline: 1.2094x; 1.1877x over previous
//
#include <hip/hip_runtime.h>
#include <hip/hip_bf16.h>

#define DEV __device__ __forceinline__

constexpr int Mn  = 30000;   // nodes (B=1)
constexpr int Tt  = 12;
constexpr int CIN = 16;
constexpr int Hh  = 64;
constexpr int Gg  = 192;     // 3H
constexpr int C2  = 128;     // 2H
constexpr int Ee  = 960000;  // edges per timestep (bidirectional)
constexpr int HC  = 128;
constexpr int Oo  = 12;
constexpr int KW  = 128;
constexpr int SEGS= 938;     // 32-row segments per t (938*32 >= 30000)
constexpr int NB  = 235;     // 128-row buckets per t (235*128 >= 30000)
constexpr int EPB = 8192;    // edges per block for bcnt/part2
constexpr int BPT = 118;     // ceil(Ee/EPB)
constexpr int CHK = 21;      // chunks per t for power iteration (252 blocks total)
constexpr int RC  = 1440;    // rows per chunk (16B-aligned chunk base; 21*1440 >= 30000)
constexpr int NRND= 76;      // 75 power rounds + 1 Rayleigh round
constexpr int NF4A= 21*256;  // phase-A float4 count (rows [r0, r0+1024) per chunk)
constexpr int NF4B= 20*104 + 44; // phase-B float4 count (rows [r0+1024, r1) per chunk)

DEV float bf2f(__hip_bfloat16 v){ return __bfloat162float(v); }
DEV __hip_bfloat16 f2bf(float v){ return __float2bfloat16(v); }
DEV float sigm(float x){ return __builtin_amdgcn_rcpf(1.f + __expf(-x)); }
DEV float tanh_f(float x){ return 1.f - 2.f*__builtin_amdgcn_rcpf(__expf(2.f*x) + 1.f); }

// agent-scope (device-coherent, sc1) accessors for cross-XCD flags/u-stores
DEV float aload_f(const float* p){ return __hip_atomic_load(p, __ATOMIC_RELAXED, __HIP_MEMORY_SCOPE_AGENT); }
DEV void  astore_f(float* p, float v){ __hip_atomic_store(p, v, __ATOMIC_RELAXED, __HIP_MEMORY_SCOPE_AGENT); }
DEV int   aload_i(const int* p){ return __hip_atomic_load(p, __ATOMIC_RELAXED, __HIP_MEMORY_SCOPE_AGENT); }
DEV void  astore_i(int* p, int v){ __hip_atomic_store(p, v, __ATOMIC_RELAXED, __HIP_MEMORY_SCOPE_AGENT); }
DEV unsigned long long aload_u64(const unsigned long long* p){ return __hip_atomic_load(p, __ATOMIC_RELAXED, __HIP_MEMORY_SCOPE_AGENT); }
DEV void astore_u64(unsigned long long* p, unsigned long long v){ __hip_atomic_store(p, v, __ATOMIC_RELAXED, __HIP_MEMORY_SCOPE_AGENT); }

typedef short bfrag8 __attribute__((ext_vector_type(8)));
typedef float ffrag4 __attribute__((ext_vector_type(4)));

// swizzled element offset into a [32 rows][64 cols] bf16 h-tile
DEV int off_h(int row, int col){
  return row*64 + ((((col >> 3) ^ (row & 7)) << 3) | (col & 7));
}

DEV short bfbits(float v){ __hip_bfloat16 b = f2bf(v); return *reinterpret_cast<short*>(&b); }

// ---------------------------------------------------------------- init (flags + CSR counters only)
__global__ void k_init(int* bcnt, int* bfill, int* flagA, unsigned long long* pbB){
  int i = blockIdx.x*256 + threadIdx.x;
  if (i < Tt*CHK*16){ flagA[i] = 0; pbB[i] = 0ull; }
  if (i < Tt*NB){ bcnt[i] = 0; bfill[i] = 0; }
}

// ---------------------------------------------------------------- stage 1: block-aggregated bucket histogram
__global__ __launch_bounds__(256) void k_bcnt(const int* __restrict__ ei, int* __restrict__ bcnt){
  __shared__ int h[NB];
  const int b = blockIdx.x;                 // 1416 = 8*177
  const int w = (b & 7)*177 + (b >> 3);
  const int t = w / BPT, ch = w - t*BPT;
  const int e0 = ch*EPB;
  const int tid = threadIdx.x;
  for (int i = tid; i < NB; i += 256) h[i] = 0;
  __syncthreads();
  #pragma unroll
  for (int i = 0; i < 32; ++i){
    int e = e0 + i*256 + tid;
    if (e < Ee){
      int r = ei[(size_t)(t*2)*Ee + e];
      atomicAdd(&h[r >> 7], 1);
    }
  }
  __syncthreads();
  for (int i = tid; i < NB; i += 256){
    int c = h[i];
    if (c > 0) atomicAdd(&bcnt[t*NB + i], c);
  }
}

// ---------------------------------------------------------------- stage 2: per-t exclusive scan of bucket counts
__global__ __launch_bounds__(256) void k_bscan(const int* __restrict__ bcnt, int* __restrict__ rpb){
  int t = blockIdx.x, tid = threadIdx.x;
  __shared__ int ps[256];
  int v = (tid < NB) ? bcnt[t*NB + tid] : 0;
  ps[tid] = v;
  __syncthreads();
  for (int o = 1; o < 256; o <<= 1){
    int x = (tid >= o) ? ps[tid-o] : 0;
    __syncthreads();
    ps[tid] += x;
    __syncthreads();
  }
  if (tid < NB) rpb[t*(NB+1) + tid] = ps[tid] - v;
  if (tid == 255) rpb[t*(NB+1) + NB] = ps[NB-1];
}

// ---------------------------------------------------------------- stage 3: partition edges into buckets (block-aggregated reservations)
__global__ __launch_bounds__(256) void k_part2(const int* __restrict__ ei, const int* __restrict__ rpb,
    int* __restrict__ bfill, unsigned* __restrict__ pair){
  __shared__ int hcnt[NB];
  __shared__ int hbase[NB];
  const int b = blockIdx.x;                 // 1416 = 8*177
  const int w = (b & 7)*177 + (b >> 3);
  const int t = w / BPT, ch = w - t*BPT;
  const int e0 = ch*EPB;
  const int tid = threadIdx.x;
  for (int i = tid; i < NB; i += 256) hcnt[i] = 0;
  __syncthreads();
  unsigned key[32];
  #pragma unroll
  for (int i = 0; i < 32; ++i){
    int e = e0 + i*256 + tid;
    unsigned k = 0xFFFFFFFFu;
    if (e < Ee){
      int r = ei[(size_t)(t*2)*Ee + e];
      int c = ei[(size_t)(t*2+1)*Ee + e];
      k = ((unsigned)r << 16) | (unsigned)c;
      atomicAdd(&hcnt[r >> 7], 1);
    }
    key[i] = k;
  }
  __syncthreads();
  for (int i = tid; i < NB; i += 256){
    int cnt = hcnt[i];
    int base = (cnt > 0) ? atomicAdd(&bfill[t*NB + i], cnt) : 0;
    hbase[i] = rpb[t*(NB+1) + i] + base;
  }
  __syncthreads();
  for (int i = tid; i < NB; i += 256) hcnt[i] = 0;
  __syncthreads();
  #pragma unroll
  for (int i = 0; i < 32; ++i){
    unsigned k = key[i];
    if (k != 0xFFFFFFFFu){
      int r = (int)(k >> 16);
      int bk = r >> 7;
      int pos = atomicAdd(&hcnt[bk], 1);
      pair[(size_t)t*Ee + hbase[bk] + pos] = ((unsigned)(r & 127) << 16) | (k & 0xFFFFu);
    }
  }
}

// ---------------------------------------------------------------- stage 4: per-bucket LDS counting sort -> col16, rp, dinv
__global__ __launch_bounds__(256) void k_csr2(const int* __restrict__ rpb, const unsigned* __restrict__ pair,
    unsigned short* __restrict__ col16, int* __restrict__ rp, float* __restrict__ dinv){
  __shared__ unsigned short cols_s[9216];
  __shared__ int lcnt[128], lfill[128];
  __shared__ int ps[256];
  const int blk = blockIdx.x;               // Tt*NB
  const int t = blk / NB, bk = blk - t*NB;
  const int r0 = bk << 7;
  const int nr = (r0 + 128 <= Mn) ? 128 : (Mn - r0);
  const int base = rpb[t*(NB+1) + bk];
  const int cnt  = rpb[t*(NB+1) + bk + 1] - base;
  const int tid = threadIdx.x;
  if (tid < 128) lcnt[tid] = 0;
  __syncthreads();
  for (int i = tid; i < cnt; i += 256){
    unsigned v = pair[(size_t)t*Ee + base + i];
    atomicAdd(&lcnt[v >> 16], 1);
  }
  __syncthreads();
  int v2 = (tid < 128) ? lcnt[tid] : 0;
  ps[tid] = v2;
  __syncthreads();
  for (int o = 1; o < 128; o <<= 1){
    int x = (tid >= o) ? ps[tid-o] : 0;
    __syncthreads();
    ps[tid] += x;
    __syncthreads();
  }
  if (tid < 128){
    int excl = ps[tid] - v2;
    lfill[tid] = excl;
    if (tid < nr){
      rp[t*(Mn+1) + r0 + tid] = base + excl;
      dinv[t*Mn + r0 + tid] = (v2 > 0) ? rsqrtf((float)v2) : 0.f;  // folded k_dinv
    }
  }
  if (bk == NB-1 && tid == 0) rp[t*(Mn+1) + Mn] = base + cnt;
  __syncthreads();
  for (int i = tid; i < cnt; i += 256){
    unsigned v = pair[(size_t)t*Ee + base + i];
    int pos = atomicAdd(&lfill[v >> 16], 1);
    cols_s[pos] = (unsigned short)(v & 0xFFFFu);
  }
  __syncthreads();
  for (int i = tid; i < cnt; i += 256)
    col16[(size_t)t*Ee + base + i] = cols_s[i];
}

// ---------------------------------------------------------------- GRU layer 0 (both dirs) via MFMA, writes y0 (T,M,128) bf16
__global__ __launch_bounds__(256) void k_gru0(
    const float* __restrict__ nf, const float* __restrict__ Wih, const float* __restrict__ Whh,
    const float* __restrict__ bih, const float* __restrict__ bhh, __hip_bfloat16* __restrict__ y0)
{
  __shared__ __hip_bfloat16 xp[Tt*32*32];   // [t][row][k]: cols 0-15 x_hi, 16-31 x_lo (24.6 KB)
  __shared__ __hip_bfloat16 h_hi[32*64];    // swizzled (4 KB)
  __shared__ __hip_bfloat16 h_lo[32*64];    // swizzled (4 KB)
  const int tid = threadIdx.x;
  const int m0  = blockIdx.x*32;
  const int lane = tid & 63, wv = tid >> 6;
  const int lr = lane & 15, lq = lane >> 4;
  for (int idx = tid; idx < Tt*32*CIN; idx += 256){
    int t = idx >> 9; int row = (idx >> 4) & 31; int k = idx & 15;
    int m = m0 + row;
    float v = (m < Mn) ? nf[((size_t)t*Mn + m)*CIN + k] : 0.f;
    __hip_bfloat16 hi = f2bf(v);
    xp[(t*32 + row)*32 + k]      = hi;
    xp[(t*32 + row)*32 + 16 + k] = f2bf(v - bf2f(hi));
  }
  for (int d = 0; d < 2; ++d){
    bfrag8 Bh[3][2], Bx[3];
    float b_r, b_z, b_in, b_hn;
    {
      const float* Wh = Whh + (size_t)d*Gg*Hh;
      const float* Wx = Wih + (size_t)d*Gg*CIN;
      #pragma unroll
      for (int c = 0; c < 3; ++c){
        int g = (wv + 4*c)*16 + lr;
        #pragma unroll
        for (int ks = 0; ks < 2; ++ks){
          bfrag8 f;
          #pragma unroll
          for (int r = 0; r < 8; ++r) f[r] = bfbits(Wh[(size_t)g*Hh + ks*32 + lq*8 + r]);
          Bh[c][ks] = f;
        }
        bfrag8 fx;
        #pragma unroll
        for (int r = 0; r < 8; ++r) fx[r] = bfbits(Wx[(size_t)g*CIN + ((lq*8 + r) & 15)]);
        Bx[c] = fx;
      }
      int j = wv*16 + lr;
      b_r  = bih[d*Gg + j]        + bhh[d*Gg + j];
      b_z  = bih[d*Gg + Hh + j]   + bhh[d*Gg + Hh + j];
      b_in = bih[d*Gg + 2*Hh + j];
      b_hn = bhh[d*Gg + 2*Hh + j];
    }
    float hreg[8];
    #pragma unroll
    for (int q = 0; q < 8; ++q) hreg[q] = 0.f;
    for (int i = tid; i < 32*64; i += 256){ h_hi[i] = f2bf(0.f); h_lo[i] = f2bf(0.f); }
    __syncthreads();
    for (int step = 0; step < Tt; ++step){
      int t = d ? (Tt-1-step) : step;
      bfrag8 xa[2], hhf[2][2], hlf[2][2];
      #pragma unroll
      for (int rt = 0; rt < 2; ++rt){
        int row = rt*16 + lr;
        xa[rt] = *(const bfrag8*)&xp[(t*32 + row)*32 + lq*8];
        #pragma unroll
        for (int ks = 0; ks < 2; ++ks){
          int e = off_h(row, ks*32 + lq*8);
          hhf[rt][ks] = *(const bfrag8*)&h_hi[e];
          hlf[rt][ks] = *(const bfrag8*)&h_lo[e];
        }
      }
      ffrag4 Cr[2], Cz[2], Cai[2], Cah[2];
      #pragma unroll
      for (int rt = 0; rt < 2; ++rt){
        ffrag4 z4 = (ffrag4){0.f,0.f,0.f,0.f};
        Cr[rt]  = __builtin_amdgcn_mfma_f32_16x16x32_bf16(xa[rt], Bx[0], z4, 0,0,0);
        Cz[rt]  = __builtin_amdgcn_mfma_f32_16x16x32_bf16(xa[rt], Bx[1], z4, 0,0,0);
        Cai[rt] = __builtin_amdgcn_mfma_f32_16x16x32_bf16(xa[rt], Bx[2], z4, 0,0,0);
        Cah[rt] = z4;
        #pragma unroll
        for (int ks = 0; ks < 2; ++ks){
          Cr[rt]  = __builtin_amdgcn_mfma_f32_16x16x32_bf16(hhf[rt][ks], Bh[0][ks], Cr[rt], 0,0,0);
          Cr[rt]  = __builtin_amdgcn_mfma_f32_16x16x32_bf16(hlf[rt][ks], Bh[0][ks], Cr[rt], 0,0,0);
          Cz[rt]  = __builtin_amdgcn_mfma_f32_16x16x32_bf16(hhf[rt][ks], Bh[1][ks], Cz[rt], 0,0,0);
          Cz[rt]  = __builtin_amdgcn_mfma_f32_16x16x32_bf16(hlf[rt][ks], Bh[1][ks], Cz[rt], 0,0,0);
          Cah[rt] = __builtin_amdgcn_mfma_f32_16x16x32_bf16(hhf[rt][ks], Bh[2][ks], Cah[rt], 0,0,0);
          Cah[rt] = __builtin_amdgcn_mfma_f32_16x16x32_bf16(hlf[rt][ks], Bh[2][ks], Cah[rt], 0,0,0);
        }
      }
      __syncthreads();
      #pragma unroll
      for (int rt = 0; rt < 2; ++rt){
        #pragma unroll
        for (int q = 0; q < 4; ++q){
          float r = sigm(Cr[rt][q] + b_r);
          float z = sigm(Cz[rt][q] + b_z);
          float n = tanh_f((Cai[rt][q] + b_in) + r*(Cah[rt][q] + b_hn));
          float h = (1.f - z)*n + z*hreg[rt*4+q];
          hreg[rt*4+q] = h;
          __hip_bfloat16 hi = f2bf(h);
          int e = off_h(rt*16 + lq*4 + q, wv*16 + lr);
          h_hi[e] = hi;
          h_lo[e] = f2bf(h - bf2f(hi));
        }
      }
      __syncthreads();
      {
        int row = tid >> 3, cg = tid & 7;
        int m = m0 + row;
        if (m < Mn){
          float4 v = *(const float4*)&h_hi[off_h(row, cg*8)];
          *(float4*)&y0[((size_t)t*Mn + m)*C2 + d*Hh + cg*8] = v;
        }
      }
    }
    __syncthreads();
  }
}

// ---------------------------------------------------------------- GRU layer 1 (reverse) via MFMA with FUSED input projection
// Projection weights converted f32->bf16 inline (k_wcvt removed; bit-identical)
__global__ __launch_bounds__(256) void k_gru1r(const __hip_bfloat16* __restrict__ y0,
    const float* __restrict__ Wp, const float* __restrict__ Whh,
    const float* __restrict__ bih, const float* __restrict__ bhh,
    const float* __restrict__ lns, const float* __restrict__ lnb,
    __hip_bfloat16* __restrict__ xbt)
{
  __shared__ __hip_bfloat16 h_hi[32*64];    // swizzled (4 KB)
  __shared__ __hip_bfloat16 h_lo[32*64];
  __shared__ float h_f32[32*72];            // exact f32 h for LayerNorm (9.2 KB)
  __shared__ float sc[Hh], bs[Hh];
  const int tid = threadIdx.x;
  const int seg = blockIdx.x;
  const int m0  = seg*32;
  const int lane = tid & 63, wv = tid >> 6;
  const int lr = lane & 15, lq = lane >> 4;
  bfrag8 Bh[3][2];
  #pragma unroll
  for (int c = 0; c < 3; ++c){
    int g = (wv + 4*c)*16 + lr;
    #pragma unroll
    for (int ks = 0; ks < 2; ++ks){
      bfrag8 f;
      #pragma unroll
      for (int r = 0; r < 8; ++r) f[r] = bfbits(Whh[(size_t)g*Hh + ks*32 + lq*8 + r]);
      Bh[c][ks] = f;
    }
  }
  bfrag8 Bp[3][4];
  #pragma unroll
  for (int c = 0; c < 3; ++c){
    int g = (wv + 4*c)*16 + lr;
    #pragma unroll
    for (int ks = 0; ks < 4; ++ks){
      bfrag8 f;
      #pragma unroll
      for (int r = 0; r < 8; ++r) f[r] = bfbits(Wp[(size_t)g*C2 + ks*32 + lq*8 + r]);
      Bp[c][ks] = f;
    }
  }
  float b_r, b_z, b_in, b_hn;
  {
    int j = wv*16 + lr;
    b_r  = bih[j]      + bhh[j];
    b_z  = bih[Hh+j]   + bhh[Hh+j];
    b_in = bih[2*Hh+j];
    b_hn = bhh[2*Hh+j];
  }
  if (tid < Hh){ sc[tid] = lns[tid]; bs[tid] = lnb[tid]; }
  float hreg[8];
  #pragma unroll
  for (int q = 0; q < 8; ++q) hreg[q] = 0.f;
  for (int i = tid; i < 32*64; i += 256){ h_hi[i] = f2bf(0.f); h_lo[i] = f2bf(0.f); }
  __syncthreads();
  for (int step = 0; step < Tt; ++step){
    int t = Tt-1-step;
    const __hip_bfloat16* yb = y0 + (size_t)t*Mn*C2;
    ffrag4 Cr[2], Cz[2], Cai[2], Cah[2];
    #pragma unroll
    for (int rt = 0; rt < 2; ++rt){
      ffrag4 z4 = (ffrag4){0.f,0.f,0.f,0.f};
      Cr[rt] = z4; Cz[rt] = z4; Cai[rt] = z4; Cah[rt] = z4;
    }
    #pragma unroll
    for (int ks = 0; ks < 4; ++ks){
      const int ko = ks*32 + lq*8;
      bfrag8 a0 = *(const bfrag8*)(yb + (size_t)(m0 + lr     )*C2 + ko);
      bfrag8 a1 = *(const bfrag8*)(yb + (size_t)(m0 + 16 + lr)*C2 + ko);
      Cr[0]  = __builtin_amdgcn_mfma_f32_16x16x32_bf16(a0, Bp[0][ks], Cr[0], 0,0,0);
      Cr[1]  = __builtin_amdgcn_mfma_f32_16x16x32_bf16(a1, Bp[0][ks], Cr[1], 0,0,0);
      Cz[0]  = __builtin_amdgcn_mfma_f32_16x16x32_bf16(a0, Bp[1][ks], Cz[0], 0,0,0);
      Cz[1]  = __builtin_amdgcn_mfma_f32_16x16x32_bf16(a1, Bp[1][ks], Cz[1], 0,0,0);
      Cai[0] = __builtin_amdgcn_mfma_f32_16x16x32_bf16(a0, Bp[2][ks], Cai[0], 0,0,0);
      Cai[1] = __builtin_amdgcn_mfma_f32_16x16x32_bf16(a1, Bp[2][ks], Cai[1], 0,0,0);
    }
    bfrag8 hhf[2][2], hlf[2][2];
    #pragma unroll
    for (int rt = 0; rt < 2; ++rt){
      int row = rt*16 + lr;
      #pragma unroll
      for (int ks = 0; ks < 2; ++ks){
        int e = off_h(row, ks*32 + lq*8);
        hhf[rt][ks] = *(const bfrag8*)&h_hi[e];
        hlf[rt][ks] = *(const bfrag8*)&h_lo[e];
      }
    }
    #pragma unroll
    for (int rt = 0; rt < 2; ++rt){
      #pragma unroll
      for (int ks = 0; ks < 2; ++ks){
        Cr[rt]  = __builtin_amdgcn_mfma_f32_16x16x32_bf16(hhf[rt][ks], Bh[0][ks], Cr[rt], 0,0,0);
        Cr[rt]  = __builtin_amdgcn_mfma_f32_16x16x32_bf16(hlf[rt][ks], Bh[0][ks], Cr[rt], 0,0,0);
        Cz[rt]  = __builtin_amdgcn_mfma_f32_16x16x32_bf16(hhf[rt][ks], Bh[1][ks], Cz[rt], 0,0,0);
        Cz[rt]  = __builtin_amdgcn_mfma_f32_16x16x32_bf16(hlf[rt][ks], Bh[1][ks], Cz[rt], 0,0,0);
        Cah[rt] = __builtin_amdgcn_mfma_f32_16x16x32_bf16(hhf[rt][ks], Bh[2][ks], Cah[rt], 0,0,0);
        Cah[rt] = __builtin_amdgcn_mfma_f32_16x16x32_bf16(hlf[rt][ks], Bh[2][ks], Cah[rt], 0,0,0);
      }
    }
    __syncthreads();
    #pragma unroll
    for (int rt = 0; rt < 2; ++rt){
      #pragma unroll
      for (int q = 0; q < 4; ++q){
        float r = sigm(Cr[rt][q] + b_r);
        float z = sigm(Cz[rt][q] + b_z);
        float n = tanh_f((Cai[rt][q] + b_in) + r*(Cah[rt][q] + b_hn));
        float h = (1.f - z)*n + z*hreg[rt*4+q];
        hreg[rt*4+q] = h;
        __hip_bfloat16 hi = f2bf(h);
        int row = rt*16 + lq*4 + q;
        int e = off_h(row, wv*16 + lr);
        h_hi[e] = hi;
        h_lo[e] = f2bf(h - bf2f(hi));
        h_f32[row*72 + wv*16 + lr] = h;
      }
    }
    __syncthreads();
    {
      int row = tid >> 3, l = tid & 7;
      float4 v0 = *(const float4*)&h_f32[row*72 + l*8];
      float4 v1 = *(const float4*)&h_f32[row*72 + l*8 + 4];
      float vals[8] = {v0.x, v0.y, v0.z, v0.w, v1.x, v1.y, v1.z, v1.w};
      float s1 = 0.f, s2 = 0.f;
      #pragma unroll
      for (int q = 0; q < 8; ++q){ s1 += vals[q]; s2 += vals[q]*vals[q]; }
      #pragma unroll
      for (int off = 1; off <= 4; off <<= 1){ s1 += __shfl_xor(s1, off); s2 += __shfl_xor(s2, off); }
      float mu  = s1 * (1.f/64.f);
      float var = s2 * (1.f/64.f) - mu*mu;
      float rs  = rsqrtf(var + 1e-5f);
      int m = m0 + row;
      if (m < Mn){
        __hip_bfloat16 ob[8];
        #pragma unroll
        for (int q = 0; q < 8; ++q){ int j = l*8 + q; ob[q] = f2bf((vals[q]-mu)*rs*sc[j] + bs[j]); }
        *(float4*)&xbt[((size_t)t*Mn + m)*Hh + l*8] = *(float4*)ob;
      }
    }
    __syncthreads();
  }
}

// ---------------------------------------------------------------- fused power iteration (R7 structure -- best measured: 1066us)
__global__ __launch_bounds__(1024) void k_pitall(const int* __restrict__ rp,
    const unsigned short* __restrict__ col, float* __restrict__ urb,
    int* __restrict__ flagA, unsigned long long* __restrict__ pbB,
    float* __restrict__ lamc)
{
  __shared__ alignas(16) float u_s[Mn];     // 120000 B
  __shared__ float redw[16];
  __shared__ float s_nrm;
  __shared__ int s_goA, s_goB;
  const int b = blockIdx.x;                 // Tt*CHK = 252
  const int t = b / CHK, ch = b - t*CHK;
  const int r0 = ch*RC;
  const int r1 = (r0 + RC < Mn) ? r0 + RC : Mn;
  const int tid = threadIdx.x;
  const int lane = tid & 63;
  const int wv   = tid >> 6;                // wave id 0..15
  const unsigned short* cp = col + (size_t)t*Ee;
  const int fS = t*CHK*16;                  // flagA slots: u32, 64B apart
  const int pS = t*CHK*16;                  // pbB slots: u64, per block 2 parity x 64B
  const int m0r = r0 + tid;                 // phase-A row
  const int m1r = m0r + 1024;               // phase-B row
  int rb0 = 0, re0 = 0, rb1 = 0, re1 = 0;
  {
    const int* rpt = rp + t*(Mn+1);
    if (m0r < r1){ rb0 = rpt[m0r]; re0 = rpt[m0r+1]; }
    if (m1r < r1){ rb1 = rpt[m1r]; re1 = rpt[m1r+1]; }
  }
  if (tid == 0){ s_nrm = 1.0f; s_goA = 0; s_goB = 0; }
  __syncthreads();
  for (int r = 1; r <= NRND; ++r){
    const int fin = (r == NRND);
    if (r == 1){
      for (int i = tid; i < Mn; i += 1024) u_s[i] = 0.005773502691896258f;
    } else {
      const int rr = r - 1;
      const float4* u4 = (const float4*)(urb + (size_t)rr*(Tt*Mn) + (size_t)t*Mn);
      float4* s4 = (float4*)u_s;
      if (wv == 0){
        const bool mine = lane < CHK;
        for (;;){ int v = mine ? aload_i(&flagA[fS + lane*16]) : 0x7FFFFFFF;
                  if (__all(v >= rr)) break; __builtin_amdgcn_s_sleep(4); }
        if (lane == 0) __hip_atomic_store(&s_goA, rr, __ATOMIC_RELAXED, __HIP_MEMORY_SCOPE_WORKGROUP);
      } else {
        while (__hip_atomic_load(&s_goA, __ATOMIC_RELAXED, __HIP_MEMORY_SCOPE_WORKGROUP) < rr)
          __builtin_amdgcn_s_sleep(2);
      }
      asm volatile("" ::: "memory");
      for (int i = tid; i < NF4A; i += 1024){
        int idx = (i >> 8)*360 + (i & 255);
        s4[idx] = u4[idx];
      }
      unsigned long long pv = 0;
      if (wv == 0){
        const bool mine = lane < CHK;
        for (;;){ pv = mine ? aload_u64(&pbB[(size_t)(pS + lane*16) + (rr & 1)*8])
                            : ((unsigned long long)rr << 32);
                  if (__all((int)(pv >> 32) == rr)) break; __builtin_amdgcn_s_sleep(4); }
        if (lane == 0) __hip_atomic_store(&s_goB, rr, __ATOMIC_RELAXED, __HIP_MEMORY_SCOPE_WORKGROUP);
      } else {
        while (__hip_atomic_load(&s_goB, __ATOMIC_RELAXED, __HIP_MEMORY_SCOPE_WORKGROUP) < rr)
          __builtin_amdgcn_s_sleep(2);
      }
      asm volatile("" ::: "memory");
      for (int i = tid; i < NF4B; i += 1024){
        int ck = i/104, off = i - ck*104;
        int idx = ck*360 + 256 + off;
        s4[idx] = u4[idx];
      }
      if (wv == 0){
        float p = (lane < CHK) ? __uint_as_float((unsigned)pv) : 0.f;
        #pragma unroll
        for (int o2 = 1; o2 < 32; o2 <<= 1) p += __shfl_xor(p, o2);
        if (tid == 0) s_nrm = p;
      }
    }
    __syncthreads();
    const float inv_s = fin ? 1.f : 1.f/(sqrtf(s_nrm) + 1e-12f);
    float* u_ot = urb + (size_t)r*(Tt*Mn);
    float local = 0.f;
    if (m0r < r1){
      float s = 0.f;
      int i = rb0;
      for (; i < re0 && (i & 3); ++i) s += u_s[cp[i]];
      for (; i + 4 <= re0; i += 4){
        ushort4 c4 = *(const ushort4*)(cp + i);
        s += (u_s[c4.x] + u_s[c4.y]) + (u_s[c4.z] + u_s[c4.w]);
      }
      for (; i < re0; ++i) s += u_s[cp[i]];
      float uv = u_s[m0r];
      float wv2 = (float)(re0 - rb0)*uv - s;
      if (!fin){ float o = inv_s*wv2; astore_f(&u_ot[t*Mn + m0r], o); local += o*o; }
      else local += uv*wv2;
    }
    asm volatile("s_waitcnt vmcnt(0)" ::: "memory");
    __syncthreads();
    if (tid == 0) astore_i(&flagA[fS + ch*16], r);
    if (m1r < r1){
      float s = 0.f;
      int i = rb1;
      for (; i < re1 && (i & 3); ++i) s += u_s[cp[i]];
      for (; i + 4 <= re1; i += 4){
        ushort4 c4 = *(const ushort4*)(cp + i);
        s += (u_s[c4.x] + u_s[c4.y]) + (u_s[c4.z] + u_s[c4.w]);
      }
      for (; i < re1; ++i) s += u_s[cp[i]];
      float uv = u_s[m1r];
      float wv2 = (float)(re1 - rb1)*uv - s;
      if (!fin){ float o = inv_s*wv2; astore_f(&u_ot[t*Mn + m1r], o); local += o*o; }
      else local += uv*wv2;
    }
    #pragma unroll
    for (int o2 = 1; o2 < 64; o2 <<= 1) local += __shfl_xor(local, o2);
    if ((tid & 63) == 0) redw[tid >> 6] = local;
    asm volatile("s_waitcnt vmcnt(0)" ::: "memory");
    __syncthreads();
    if (tid < 64){
      float tot = (tid < 16) ? redw[tid] : 0.f;
      #pragma unroll
      for (int o2 = 1; o2 < 16; o2 <<= 1) tot += __shfl_xor(tot, o2);
      if (tid == 0){
        unsigned long long out = ((unsigned long long)r << 32)
                               | (unsigned long long)__float_as_uint(tot);
        astore_u64(&pbB[(size_t)(pS + ch*16) + (r & 1)*8], out);
      }
    }
  }
  if (ch == 0 && tid < 64){
    const bool mine = lane < CHK;
    unsigned long long pv = 0;
    for (;;){ pv = mine ? aload_u64(&pbB[(size_t)(pS + lane*16) + (NRND & 1)*8])
                        : ((unsigned long long)NRND << 32);
              if (__all((int)(pv >> 32) == NRND)) break; __builtin_amdgcn_s_sleep(4); }
    float p = mine ? __uint_as_float((unsigned)pv) : 0.f;
    #pragma unroll
    for (int o2 = 1; o2 < 32; o2 <<= 1) p += __shfl_xor(p, o2);
    if (tid == 0){
      float nn = sqrtf(s_nrm) + 1e-12f;
      float lam = p / (nn*nn);
      lamc[2*t+0] = -2.f/lam;
      lamc[2*t+1] =  2.f/lam - 1.f;
    }
  }
}

// ---------------------------------------------------------------- Chebyshev SpMM (wave per row, lane = channel, XCD-swizzled)
__global__ __launch_bounds__(256) void k_cheb(const __hip_bfloat16* __restrict__ xin,
    const __hip_bfloat16* __restrict__ xb0, __hip_bfloat16* __restrict__ outp,
    const int* __restrict__ rp, const unsigned short* __restrict__ col,
    const float* __restrict__ dinv, const float* __restrict__ lamc, float s1, float s2)
{
  const int blk = blockIdx.x;               // 90000 = 8*11250
  const int w = (blk & 7)*11250 + (blk >> 3);
  const int gw = w*4 + (threadIdx.x >> 6);
  const int lane = threadIdx.x & 63;
  int t = gw / Mn, m = gw - t*Mn;
  float coef = lamc[2*t], diag = lamc[2*t+1];
  const __hip_bfloat16* xt = xin + (size_t)t*Mn*Hh;
  const float* dv = dinv + t*Mn;
  float acc = diag * bf2f(xt[(size_t)m*Hh + lane]);
  float cdm = coef * dv[m];
  int bgn = rp[t*(Mn+1)+m], end = rp[t*(Mn+1)+m+1];
  const unsigned short* cp = col + (size_t)t*Ee;
  int i = bgn;
  for (; i < end && (i & 3); ++i){ int c = cp[i]; acc += (cdm*dv[c])*bf2f(xt[(size_t)c*Hh + lane]); }
  for (; i + 4 <= end; i += 4){
    ushort4 c4 = *(const ushort4*)(cp + i);
    float w0 = cdm*dv[c4.x], w1 = cdm*dv[c4.y], w2 = cdm*dv[c4.z], w3 = cdm*dv[c4.w];
    acc += w0*bf2f(xt[(size_t)c4.x*Hh + lane]);
    acc += w1*bf2f(xt[(size_t)c4.y*Hh + lane]);
    acc += w2*bf2f(xt[(size_t)c4.z*Hh + lane]);
    acc += w3*bf2f(xt[(size_t)c4.w*Hh + lane]);
  }
  for (; i < end; ++i){ int c = cp[i]; acc += (cdm*dv[c])*bf2f(xt[(size_t)c*Hh + lane]); }
  float o = s1*acc;
  if (s2 != 0.f) o += s2*bf2f(xb0[(size_t)gw*Hh + lane]);
  outp[(size_t)gw*Hh + lane] = f2bf(o);
}

// ---------------------------------------------------------------- fold cheb_W into conv_W
__global__ void k_ww(const float* __restrict__ chebW, const float* __restrict__ chebb,
    const float* __restrict__ convW, const float* __restrict__ convb, float* __restrict__ WW, float* __restrict__ c0)
{
  int idx = blockIdx.x*256 + threadIdx.x;
  if (idx < 3*Tt*Hh*Oo){
    int oc = idx % Oo; int j = (idx/Oo) % Hh; int t = (idx/(Oo*Hh)) % Tt; int i = idx/(Oo*Hh*Tt);
    const float* cw = chebW + ((size_t)i*Hh + j)*HC + (HC-KW);
    const float* vw = convW + ((size_t)oc*Tt + t)*KW;
    float s = 0.f;
    for (int k = 0; k < KW; ++k) s += cw[k]*vw[k];
    WW[idx] = s;
  }
  if (blockIdx.x == 0 && threadIdx.x < Oo){
    int oc = threadIdx.x;
    float s = convb[oc];
    for (int t = 0; t < Tt; ++t){
      const float* vw = convW + ((size_t)oc*Tt + t)*KW;
      for (int k = 0; k < KW; ++k) s += chebb[(HC-KW)+k]*vw[k];
    }
    c0[oc] = s;
  }
}

// ---------------------------------------------------------------- fused cheb-GEMM + temporal conv + sigmoid
__global__ __launch_bounds__(256) void k_final(const __hip_bfloat16* __restrict__ tx0,
    const __hip_bfloat16* __restrict__ tx1, const __hip_bfloat16* __restrict__ tx2,
    const float* __restrict__ WW, const float* __restrict__ c0, float* __restrict__ outp)
{
  __shared__ float xs[64][65];
  __shared__ float ww[64][12];
  const int tid = threadIdx.x;
  const int n0 = blockIdx.x*64;
  const int n = tid & 63, ob = (tid >> 6)*3;
  float acc[3] = {0.f, 0.f, 0.f};
  for (int it = 0; it < 3*Tt; ++it){
    int ii = it / Tt, t = it % Tt;
    const __hip_bfloat16* tx = (ii == 0) ? tx0 : (ii == 1) ? tx1 : tx2;
    __syncthreads();
    // vectorized staging: ushort4 = 4 bf16 per lane (was scalar bf16 loads)
    for (int idx = tid; idx < 64*16; idx += 256){
      int mm = idx >> 4, j4 = idx & 15;
      int m = n0 + mm;
      if (m < Mn){
        ushort4 v = *(const ushort4*)(tx + ((size_t)t*Mn + m)*Hh + j4*4);
        xs[mm][j4*4+0] = bf2f(*(__hip_bfloat16*)&v.x);
        xs[mm][j4*4+1] = bf2f(*(__hip_bfloat16*)&v.y);
        xs[mm][j4*4+2] = bf2f(*(__hip_bfloat16*)&v.z);
        xs[mm][j4*4+3] = bf2f(*(__hip_bfloat16*)&v.w);
      } else {
        xs[mm][j4*4+0] = 0.f; xs[mm][j4*4+1] = 0.f;
        xs[mm][j4*4+2] = 0.f; xs[mm][j4*4+3] = 0.f;
      }
    }
    for (int idx = tid; idx < 64*Oo; idx += 256)
      ((float*)ww)[idx] = WW[((size_t)(ii*Tt + t)*Hh)*Oo + idx];
    __syncthreads();
    #pragma unroll 8
    for (int j = 0; j < 64; ++j){
      float x = xs[n][j];
      acc[0] += x*ww[j][ob+0];
      acc[1] += x*ww[j][ob+1];
      acc[2] += x*ww[j][ob+2];
    }
  }
  int m = n0 + n;
  if (m < Mn){
    #pragma unroll
    for (int q = 0; q < 3; ++q) outp[(size_t)m*Oo + ob + q] = sigm(acc[q] + c0[ob+q]);
  }
}

// ================================================================ host
extern "C" void kernel_launch(void* const* d_in, const int* in_sizes, int n_in,
                              void* d_out, int out_size, void* d_ws, size_t ws_size,
                              hipStream_t stream)
{
  const float* nf    = (const float*)d_in[0];
  const int*   ei    = (const int*)d_in[1];
  const float* Wih0  = (const float*)d_in[2];
  const float* Whh0  = (const float*)d_in[3];
  const float* bih0  = (const float*)d_in[4];
  const float* bhh0  = (const float*)d_in[5];
  const float* Wih1  = (const float*)d_in[6];
  const float* Whh1  = (const float*)d_in[7];
  const float* bih1  = (const float*)d_in[8];
  const float* bhh1  = (const float*)d_in[9];
  const float* lns   = (const float*)d_in[10];
  const float* lnb   = (const float*)d_in[11];
  const float* chebW = (const float*)d_in[12];
  const float* chebb = (const float*)d_in[13];
  const float* convW = (const float*)d_in[14];
  const float* convb = (const float*)d_in[15];
  float* outp = (float*)d_out;

  char* base = (char*)d_ws;
  size_t off = 0;
  auto alloc = [&](size_t bytes)->char*{ char* p = base + off; off += (bytes + 255) & ~(size_t)255; return p; };

  __hip_bfloat16* y0  = (__hip_bfloat16*)alloc((size_t)Tt*Mn*C2*2);
  __hip_bfloat16* tx1 = y0;
  __hip_bfloat16* tx2 = y0 + (size_t)Tt*Mn*Hh;
  // shared arena: pair (46.1 MB, dead after k_csr2) then urb (110.9 MB)
  char* arena = alloc((size_t)(NRND+1)*Tt*Mn*4);
  unsigned* pair = (unsigned*)arena;
  float*    urb  = (float*)arena;
  __hip_bfloat16* xbt = (__hip_bfloat16*)alloc((size_t)Tt*Mn*Hh*2);
  unsigned short* col16 = (unsigned short*)alloc((size_t)Tt*Ee*2);
  int*   rp   = (int*)alloc((size_t)Tt*(Mn+1)*4);
  int*   bcnt = (int*)alloc((size_t)Tt*NB*4);
  int*   bfill= (int*)alloc((size_t)Tt*NB*4);
  int*   rpb  = (int*)alloc((size_t)Tt*(NB+1)*4);
  float* dinv = (float*)alloc((size_t)Tt*Mn*4);
  float* lamc = (float*)alloc((size_t)2*Tt*4);
  float* WW   = (float*)alloc((size_t)3*Tt*Hh*Oo*4);
  float* c0   = (float*)alloc((size_t)Oo*4);
  int*   flagA = (int*)alloc((size_t)Tt*CHK*16*4);              // phase-A epoch flags, 64B apart
  unsigned long long* pbB = (unsigned long long*)alloc((size_t)Tt*CHK*16*8); // packed {epoch,partial}
  (void)ws_size; (void)in_sizes; (void)n_in; (void)out_size;

  // CSR build: bucket histogram -> bucket scan -> partition -> per-bucket counting sort (emits rp+dinv)
  k_init<<<16, 256, 0, stream>>>(bcnt, bfill, flagA, pbB);
  k_bcnt<<<Tt*BPT, 256, 0, stream>>>(ei, bcnt);
  k_bscan<<<Tt, 256, 0, stream>>>(bcnt, rpb);
  k_part2<<<Tt*BPT, 256, 0, stream>>>(ei, rpb, bfill, pair);
  k_csr2<<<Tt*NB, 256, 0, stream>>>(rpb, pair, col16, rp, dinv);

  // GRU stack (MFMA; projection fused into gru1r, weights converted inline)
  k_gru0<<<SEGS, 256, 0, stream>>>(nf, Wih0, Whh0, bih0, bhh0, y0);
  k_gru1r<<<SEGS, 256, 0, stream>>>(y0, Wih1 + (size_t)Gg*C2, Whh1 + (size_t)Gg*Hh,
                                    bih1 + Gg, bhh1 + Gg, lns, lnb, xbt);

  // power iteration: 75 rounds + 1 Rayleigh round, fused into ONE kernel (R7 structure)
  k_pitall<<<Tt*CHK, 1024, 0, stream>>>(rp, col16, urb, flagA, pbB, lamc);

  // Chebyshev: tx1 = Lhat(x), tx2 = 2*Lhat(tx1) - x
  k_cheb<<<(Tt*Mn)/4, 256, 0, stream>>>(xbt, xbt, tx1, rp, col16, dinv, lamc, 1.f, 0.f);
  k_cheb<<<(Tt*Mn)/4, 256, 0, stream>>>(tx1, xbt, tx2, rp, col16, dinv, lamc, 2.f, -1.f);

  // folded cheb-GEMM + conv + sigmoid
  k_ww<<<(3*Tt*Hh*Oo + 255)/256, 256, 0, stream>>>(chebW, chebb, convW, convb, WW, c0);
  k_final<<<(Mn + 63)/64, 256, 0, stream>>>(xbt, tx1, tx2, WW, c0, outp);
}